// Round 1
// baseline (14723.181 us; speedup 1.0000x reference)
//
#include <hip/hip_runtime.h>
#include <hip/hip_bf16.h>
#include <math.h>

#define TT 2048
#define BB 2
#define VV 32000
#define DD 512
#define HH 8
#define HSS 64
#define LL 4
#define FF_ 2048

// ---------------- embedding: x[b,t,:] = tok_emb[idx[b,t],:] + pos_emb[t,:]
__global__ __launch_bounds__(64)
void embed_kernel(const int* __restrict__ idx, const float* __restrict__ tok,
                  const float* __restrict__ pos, float* __restrict__ x)
{
    int row = blockIdx.x;            // b*T + t
    int t = row & (TT - 1);
    int tokid = idx[row];
    int lane = threadIdx.x;
    const float4* tp = (const float4*)(tok + (size_t)tokid * DD);
    const float4* pp = (const float4*)(pos + (size_t)t * DD);
    float4* xp = (float4*)(x + (size_t)row * DD);
    int i0 = lane * 2;
    float4 a = tp[i0],   b4 = pp[i0];
    float4 c = tp[i0+1], d4 = pp[i0+1];
    xp[i0]   = make_float4(a.x + b4.x, a.y + b4.y, a.z + b4.z, a.w + b4.w);
    xp[i0+1] = make_float4(c.x + d4.x, c.y + d4.y, c.z + d4.z, c.w + d4.w);
}

// ---------------- layernorm: wave per row (D=512, lane handles 8 elems)
__global__ __launch_bounds__(256)
void ln_kernel(const float* __restrict__ x, const float* __restrict__ g,
               const float* __restrict__ b, float* __restrict__ out)
{
    int wave = threadIdx.x >> 6;
    int lane = threadIdx.x & 63;
    int row  = blockIdx.x * 4 + wave;
    const float* xr = x + (size_t)row * DD;
    float4 v0 = *(const float4*)(xr + lane * 8);
    float4 v1 = *(const float4*)(xr + lane * 8 + 4);
    float s = v0.x + v0.y + v0.z + v0.w + v1.x + v1.y + v1.z + v1.w;
    float q = v0.x*v0.x + v0.y*v0.y + v0.z*v0.z + v0.w*v0.w
            + v1.x*v1.x + v1.y*v1.y + v1.z*v1.z + v1.w*v1.w;
    #pragma unroll
    for (int off = 32; off; off >>= 1) {
        s += __shfl_xor(s, off);
        q += __shfl_xor(q, off);
    }
    float mu  = s * (1.0f / DD);
    float var = q * (1.0f / DD) - mu * mu;
    float rs  = rsqrtf(var + 1e-5f);
    float4 g0 = *(const float4*)(g + lane * 8);
    float4 g1 = *(const float4*)(g + lane * 8 + 4);
    float4 b0 = *(const float4*)(b + lane * 8);
    float4 b1 = *(const float4*)(b + lane * 8 + 4);
    float4 o0, o1;
    o0.x = (v0.x - mu) * rs * g0.x + b0.x;
    o0.y = (v0.y - mu) * rs * g0.y + b0.y;
    o0.z = (v0.z - mu) * rs * g0.z + b0.z;
    o0.w = (v0.w - mu) * rs * g0.w + b0.w;
    o1.x = (v1.x - mu) * rs * g1.x + b1.x;
    o1.y = (v1.y - mu) * rs * g1.y + b1.y;
    o1.z = (v1.z - mu) * rs * g1.z + b1.z;
    o1.w = (v1.w - mu) * rs * g1.w + b1.w;
    float* orow = out + (size_t)row * DD;
    *(float4*)(orow + lane * 8)     = o0;
    *(float4*)(orow + lane * 8 + 4) = o1;
}

// ---------------- generic fp32 GEMM: C[64x64 tiles] = A@B (+bias)(+resid)(relu)
// strideBx != 0: per-column-tile B pointer = B + bx*strideBx (ldb-wide local block)
// All M,N,K multiples of 64/64/16 in this model — no bounds checks.
__global__ __launch_bounds__(256)
void gemm_kernel(const float* __restrict__ A, int lda,
                 const float* __restrict__ B, int ldb, int strideBx,
                 float* __restrict__ C, int ldc,
                 const float* __restrict__ bias,
                 const float* __restrict__ resid, int ldres,
                 int K, int relu)
{
    __shared__ float As[16][68];
    __shared__ float Bs[16][68];
    const int bx = blockIdx.x, by = blockIdx.y;
    const int m0 = by << 6;
    const int n0 = bx << 6;
    const float* Bp = strideBx ? (B + (size_t)bx * (size_t)strideBx) : (B + n0);
    const float* Ap = A + (size_t)m0 * lda;
    const int tid = threadIdx.x;
    const int tn = tid & 15, tm = tid >> 4;
    const int ak = tid & 15, am = tid >> 4;   // A loads: k, row-group
    const int bn = tid & 63, bk = tid >> 6;   // B loads: n, k-group
    float acc[4][4] = {};

    for (int k0 = 0; k0 < K; k0 += 16) {
        #pragma unroll
        for (int i = 0; i < 4; ++i)
            As[ak][am + i * 16] = Ap[(size_t)(am + i * 16) * lda + k0 + ak];
        #pragma unroll
        for (int i = 0; i < 4; ++i)
            Bs[bk + i * 4][bn] = Bp[(size_t)(k0 + bk + i * 4) * ldb + bn];
        __syncthreads();
        #pragma unroll
        for (int k = 0; k < 16; ++k) {
            float4 av = *(const float4*)&As[k][tm * 4];
            float4 bv = *(const float4*)&Bs[k][tn * 4];
            const float* ar = &av.x;
            const float* br = &bv.x;
            #pragma unroll
            for (int i = 0; i < 4; ++i)
                #pragma unroll
                for (int j = 0; j < 4; ++j)
                    acc[i][j] += ar[i] * br[j];
        }
        __syncthreads();
    }

    #pragma unroll
    for (int i = 0; i < 4; ++i) {
        int mm = m0 + tm * 4 + i;
        #pragma unroll
        for (int j = 0; j < 4; ++j) {
            int gn = n0 + tn * 4 + j;
            float v = acc[i][j];
            if (bias)  v += bias[gn];
            if (resid) v += resid[(size_t)mm * ldres + gn];
            if (relu)  v = fmaxf(v, 0.0f);
            C[(size_t)mm * ldc + gn] = v;
        }
    }
}

// ---------------- attention: one wave per (b,h,t) row, online softmax.
// q,k,v layout [B,T,H*HS]; scale = 1/sqrt(D) per the reference (not 1/sqrt(HS)).
__global__ __launch_bounds__(256)
void attn_kernel(const float* __restrict__ q, const float* __restrict__ k,
                 const float* __restrict__ v, float* __restrict__ out)
{
    const int wave = threadIdx.x >> 6, lane = threadIdx.x & 63;
    const int t = blockIdx.x * 4 + wave;
    const int z = blockIdx.y;            // b*H + h
    const int b = z >> 3, h = z & 7;
    const size_t rowbase = ((size_t)(b * TT + t)) * DD + h * HSS;
    const float scale = 0.04419417382415922f;  // 1/sqrt(512)
    float qe = q[rowbase + lane] * scale;
    float m = -INFINITY, l = 0.f, acc = 0.f;
    for (int s = 0; s <= t; ++s) {
        const size_t kb = ((size_t)(b * TT + s)) * DD + h * HSS;
        float p = qe * k[kb + lane];
        #pragma unroll
        for (int off = 32; off; off >>= 1) p += __shfl_xor(p, off);
        float nm = fmaxf(m, p);
        float c = __expf(m - nm);
        float w = __expf(p - nm);
        l   = l * c + w;
        acc = acc * c + w * v[kb + lane];
        m = nm;
    }
    out[rowbase + lane] = acc / l;
}

// ---------------- per-row -log-softmax[target]
__global__ __launch_bounds__(256)
void rowloss_kernel(const float* __restrict__ logits, const int* __restrict__ targets,
                    float* __restrict__ rowloss)
{
    __shared__ float red[256];
    const int row = blockIdx.x, tid = threadIdx.x;
    const float* lr = logits + (size_t)row * VV;
    float mx = -INFINITY;
    for (int i = tid; i < VV; i += 256) mx = fmaxf(mx, lr[i]);
    red[tid] = mx; __syncthreads();
    for (int s2 = 128; s2; s2 >>= 1) {
        if (tid < s2) red[tid] = fmaxf(red[tid], red[tid + s2]);
        __syncthreads();
    }
    mx = red[0]; __syncthreads();
    float s = 0.f;
    for (int i = tid; i < VV; i += 256) s += __expf(lr[i] - mx);
    red[tid] = s; __syncthreads();
    for (int s2 = 128; s2; s2 >>= 1) {
        if (tid < s2) red[tid] += red[tid + s2];
        __syncthreads();
    }
    if (tid == 0) rowloss[row] = -(lr[targets[row]] - mx - logf(red[0]));
}

__global__ __launch_bounds__(256)
void loss_finalize(const float* __restrict__ rowloss, float* __restrict__ out)
{
    __shared__ float red[256];
    float s = 0.f;
    for (int i = threadIdx.x; i < BB * TT; i += 256) s += rowloss[i];
    red[threadIdx.x] = s; __syncthreads();
    for (int s2 = 128; s2; s2 >>= 1) {
        if (threadIdx.x < s2) red[threadIdx.x] += red[threadIdx.x + s2];
        __syncthreads();
    }
    if (threadIdx.x == 0) out[0] = red[0] * (1.0f / (BB * TT));
}

extern "C" void kernel_launch(void* const* d_in, const int* in_sizes, int n_in,
                              void* d_out, int out_size, void* d_ws, size_t ws_size,
                              hipStream_t stream) {
    const int*   idx     = (const int*)  d_in[0];
    const int*   targets = (const int*)  d_in[1];
    const float* tok_emb = (const float*)d_in[2];
    const float* pos_emb = (const float*)d_in[3];
    const float* ln1_g   = (const float*)d_in[4];
    const float* ln1_b   = (const float*)d_in[5];
    const float* Wq      = (const float*)d_in[6];
    const float* Wk      = (const float*)d_in[7];
    const float* Wv      = (const float*)d_in[8];
    const float* Wo      = (const float*)d_in[9];
    const float* bo      = (const float*)d_in[10];
    const float* ln2_g   = (const float*)d_in[11];
    const float* ln2_b   = (const float*)d_in[12];
    const float* W1      = (const float*)d_in[13];
    const float* b1      = (const float*)d_in[14];
    const float* W2      = (const float*)d_in[15];
    const float* b2      = (const float*)d_in[16];
    const float* lnf_g   = (const float*)d_in[17];
    const float* lnf_b   = (const float*)d_in[18];
    const float* Wout    = (const float*)d_in[19];
    const float* bout    = (const float*)d_in[20];

    float* out    = (float*)d_out;
    float* logits = out + 1;                    // [B*T, V]

    // workspace layout (floats): x | h | qkv-region (ff aliases qkv) | rowloss
    float* ws = (float*)d_ws;
    const size_t ROW = (size_t)BB * TT;         // 4096
    float* x  = ws;                             // ROW*DD
    float* h  = x + ROW * DD;                   // ROW*DD  (also attnout)
    float* qb = h + ROW * DD;                   // ROW*DD
    float* kb = qb + ROW * DD;                  // ROW*DD
    float* vb = kb + ROW * DD;                  // ROW*DD
    float* ff = qb;                             // ROW*FF_ (aliases q,k,v + extra)
    float* rowloss = qb + ROW * FF_;            // ROW

    const size_t WQKV_L = (size_t)HH * DD * HSS;   // per-layer W{q,k,v} stride
    const size_t WO_L   = (size_t)DD * DD;
    const size_t W1_L   = (size_t)DD * FF_;
    const size_t W2_L   = (size_t)FF_ * DD;

    embed_kernel<<<ROW, 64, 0, stream>>>(idx, tok_emb, pos_emb, x);

    for (int l = 0; l < LL; ++l) {
        ln_kernel<<<ROW / 4, 256, 0, stream>>>(x, ln1_g + l * DD, ln1_b + l * DD, h);

        // q,k,v: [4096,512] @ per-head [512,64] blocks -> [B,T,H*HS]
        gemm_kernel<<<dim3(DD / 64, ROW / 64), 256, 0, stream>>>(
            h, DD, Wq + l * WQKV_L, HSS, DD * HSS, qb, DD, nullptr, nullptr, 0, DD, 0);
        gemm_kernel<<<dim3(DD / 64, ROW / 64), 256, 0, stream>>>(
            h, DD, Wk + l * WQKV_L, HSS, DD * HSS, kb, DD, nullptr, nullptr, 0, DD, 0);
        gemm_kernel<<<dim3(DD / 64, ROW / 64), 256, 0, stream>>>(
            h, DD, Wv + l * WQKV_L, HSS, DD * HSS, vb, DD, nullptr, nullptr, 0, DD, 0);

        attn_kernel<<<dim3(TT / 4, BB * HH), 256, 0, stream>>>(qb, kb, vb, h);

        // x = x + attn @ Wo + bo
        gemm_kernel<<<dim3(DD / 64, ROW / 64), 256, 0, stream>>>(
            h, DD, Wo + l * WO_L, DD, 0, x, DD, bo + l * DD, x, DD, DD, 0);

        ln_kernel<<<ROW / 4, 256, 0, stream>>>(x, ln2_g + l * DD, ln2_b + l * DD, h);

        // ff = relu(h @ W1 + b1)
        gemm_kernel<<<dim3(FF_ / 64, ROW / 64), 256, 0, stream>>>(
            h, DD, W1 + l * W1_L, FF_, 0, ff, FF_, b1 + l * FF_, nullptr, 0, DD, 1);

        // x = x + ff @ W2 + b2
        gemm_kernel<<<dim3(DD / 64, ROW / 64), 256, 0, stream>>>(
            ff, FF_, W2 + l * W2_L, DD, 0, x, DD, b2 + l * DD, x, DD, FF_, 0);
    }

    ln_kernel<<<ROW / 4, 256, 0, stream>>>(x, lnf_g, lnf_b, h);

    // logits = h @ Wout + bout  (written directly to d_out+1, scalar stores)
    gemm_kernel<<<dim3(VV / 64, ROW / 64), 256, 0, stream>>>(
        h, DD, Wout, VV, 0, logits, VV, bout, nullptr, 0, DD, 0);

    rowloss_kernel<<<ROW, 256, 0, stream>>>(logits, targets, rowloss);
    loss_finalize<<<1, 256, 0, stream>>>(rowloss, out);
}

// Round 3
// 5044.897 us; speedup vs baseline: 2.9184x; 2.9184x over previous
//
#include <hip/hip_runtime.h>
#include <hip/hip_bf16.h>
#include <math.h>

#define TT 2048
#define BB 2
#define VV 32000
#define DD 512
#define HH 8
#define HSS 64
#define LL 4
#define FF_ 2048

// ---------------- embedding: x[b,t,:] = tok_emb[idx[b,t],:] + pos_emb[t,:]
__global__ __launch_bounds__(64)
void embed_kernel(const int* __restrict__ idx, const float* __restrict__ tok,
                  const float* __restrict__ pos, float* __restrict__ x)
{
    int row = blockIdx.x;            // b*T + t
    int t = row & (TT - 1);
    int tokid = idx[row];
    int lane = threadIdx.x;
    const float4* tp = (const float4*)(tok + (size_t)tokid * DD);
    const float4* pp = (const float4*)(pos + (size_t)t * DD);
    float4* xp = (float4*)(x + (size_t)row * DD);
    int i0 = lane * 2;
    float4 a = tp[i0],   b4 = pp[i0];
    float4 c = tp[i0+1], d4 = pp[i0+1];
    xp[i0]   = make_float4(a.x + b4.x, a.y + b4.y, a.z + b4.z, a.w + b4.w);
    xp[i0+1] = make_float4(c.x + d4.x, c.y + d4.y, c.z + d4.z, c.w + d4.w);
}

// ---------------- layernorm: wave per row (D=512, lane handles 8 elems)
__global__ __launch_bounds__(256)
void ln_kernel(const float* __restrict__ x, const float* __restrict__ g,
               const float* __restrict__ b, float* __restrict__ out)
{
    int wave = threadIdx.x >> 6;
    int lane = threadIdx.x & 63;
    int row  = blockIdx.x * 4 + wave;
    const float* xr = x + (size_t)row * DD;
    float4 v0 = *(const float4*)(xr + lane * 8);
    float4 v1 = *(const float4*)(xr + lane * 8 + 4);
    float s = v0.x + v0.y + v0.z + v0.w + v1.x + v1.y + v1.z + v1.w;
    float q = v0.x*v0.x + v0.y*v0.y + v0.z*v0.z + v0.w*v0.w
            + v1.x*v1.x + v1.y*v1.y + v1.z*v1.z + v1.w*v1.w;
    #pragma unroll
    for (int off = 32; off; off >>= 1) {
        s += __shfl_xor(s, off);
        q += __shfl_xor(q, off);
    }
    float mu  = s * (1.0f / DD);
    float var = q * (1.0f / DD) - mu * mu;
    float rs  = rsqrtf(var + 1e-5f);
    float4 g0 = *(const float4*)(g + lane * 8);
    float4 g1 = *(const float4*)(g + lane * 8 + 4);
    float4 b0 = *(const float4*)(b + lane * 8);
    float4 b1 = *(const float4*)(b + lane * 8 + 4);
    float4 o0, o1;
    o0.x = (v0.x - mu) * rs * g0.x + b0.x;
    o0.y = (v0.y - mu) * rs * g0.y + b0.y;
    o0.z = (v0.z - mu) * rs * g0.z + b0.z;
    o0.w = (v0.w - mu) * rs * g0.w + b0.w;
    o1.x = (v1.x - mu) * rs * g1.x + b1.x;
    o1.y = (v1.y - mu) * rs * g1.y + b1.y;
    o1.z = (v1.z - mu) * rs * g1.z + b1.z;
    o1.w = (v1.w - mu) * rs * g1.w + b1.w;
    float* orow = out + (size_t)row * DD;
    *(float4*)(orow + lane * 8)     = o0;
    *(float4*)(orow + lane * 8 + 4) = o1;
}

// ---------------- generic fp32 GEMM: C[64x64 tiles] = A@B (+bias)(+resid)(relu)
__global__ __launch_bounds__(256)
void gemm_kernel(const float* __restrict__ A, int lda,
                 const float* __restrict__ B, int ldb, int strideBx,
                 float* __restrict__ C, int ldc,
                 const float* __restrict__ bias,
                 const float* __restrict__ resid, int ldres,
                 int K, int relu)
{
    __shared__ float As[16][68];
    __shared__ float Bs[16][68];
    const int bx = blockIdx.x, by = blockIdx.y;
    const int m0 = by << 6;
    const int n0 = bx << 6;
    const float* Bp = strideBx ? (B + (size_t)bx * (size_t)strideBx) : (B + n0);
    const float* Ap = A + (size_t)m0 * lda;
    const int tid = threadIdx.x;
    const int tn = tid & 15, tm = tid >> 4;
    const int ak = tid & 15, am = tid >> 4;   // A loads: k, row-group
    const int bn = tid & 63, bk = tid >> 6;   // B loads: n, k-group
    float acc[4][4] = {};

    for (int k0 = 0; k0 < K; k0 += 16) {
        #pragma unroll
        for (int i = 0; i < 4; ++i)
            As[ak][am + i * 16] = Ap[(size_t)(am + i * 16) * lda + k0 + ak];
        #pragma unroll
        for (int i = 0; i < 4; ++i)
            Bs[bk + i * 4][bn] = Bp[(size_t)(k0 + bk + i * 4) * ldb + bn];
        __syncthreads();
        #pragma unroll
        for (int k = 0; k < 16; ++k) {
            float4 av = *(const float4*)&As[k][tm * 4];
            float4 bv = *(const float4*)&Bs[k][tn * 4];
            const float* ar = &av.x;
            const float* br = &bv.x;
            #pragma unroll
            for (int i = 0; i < 4; ++i)
                #pragma unroll
                for (int j = 0; j < 4; ++j)
                    acc[i][j] += ar[i] * br[j];
        }
        __syncthreads();
    }

    #pragma unroll
    for (int i = 0; i < 4; ++i) {
        int mm = m0 + tm * 4 + i;
        #pragma unroll
        for (int j = 0; j < 4; ++j) {
            int gn = n0 + tn * 4 + j;
            float v = acc[i][j];
            if (bias)  v += bias[gn];
            if (resid) v += resid[(size_t)mm * ldres + gn];
            if (relu)  v = fmaxf(v, 0.0f);
            C[(size_t)mm * ldc + gn] = v;
        }
    }
}

// ---------------- tiled flash attention (fp32)
// One block per (b,h, 64-query tile). 256 threads, 4x4 microtile per thread.
// scale = 1/sqrt(D) per the reference (not 1/sqrt(HS)).
__global__ __launch_bounds__(256)
void attn_tile_kernel(const float* __restrict__ q, const float* __restrict__ k,
                      const float* __restrict__ v, float* __restrict__ out)
{
    __shared__ float Qt[64][68];   // Qt[d][row], pre-scaled
    __shared__ float Kt[64][68];   // Kt[d][key]
    __shared__ float Vs[64][68];   // Vs[key][d]
    __shared__ float Pt[64][68];   // Pt[key][row]

    const int z = blockIdx.y, b = z >> 3, h = z & 7;
    const int q0 = blockIdx.x << 6;
    const int tid = threadIdx.x;
    const int tn = tid & 15, tm = tid >> 4;
    const int lrow = tid >> 2;          // 0..63 (global load row)
    const int ld0  = (tid & 3) << 4;    // 0,16,32,48 (global load d-offset)

    const float scale = 0.04419417382415922f;  // 1/sqrt(512)

    // load Q tile transposed + scaled
    {
        const float* qp = q + ((size_t)(b * TT + q0 + lrow)) * DD + h * HSS + ld0;
        #pragma unroll
        for (int i = 0; i < 4; ++i) {
            float4 val = *(const float4*)(qp + i * 4);
            Qt[ld0 + i*4 + 0][lrow] = val.x * scale;
            Qt[ld0 + i*4 + 1][lrow] = val.y * scale;
            Qt[ld0 + i*4 + 2][lrow] = val.z * scale;
            Qt[ld0 + i*4 + 3][lrow] = val.w * scale;
        }
    }

    float acc[4][4] = {};
    float mreg[4] = {-1e30f, -1e30f, -1e30f, -1e30f};
    float lreg[4] = {};

    for (int s0 = 0; s0 <= q0; s0 += 64) {
        __syncthreads();   // previous PV done before overwriting K/V
        {
            const float* kp = k + ((size_t)(b * TT + s0 + lrow)) * DD + h * HSS + ld0;
            const float* vp = v + ((size_t)(b * TT + s0 + lrow)) * DD + h * HSS + ld0;
            #pragma unroll
            for (int i = 0; i < 4; ++i) {
                float4 kv = *(const float4*)(kp + i * 4);
                Kt[ld0 + i*4 + 0][lrow] = kv.x;
                Kt[ld0 + i*4 + 1][lrow] = kv.y;
                Kt[ld0 + i*4 + 2][lrow] = kv.z;
                Kt[ld0 + i*4 + 3][lrow] = kv.w;
                *(float4*)(&Vs[lrow][ld0 + i*4]) = *(const float4*)(vp + i * 4);
            }
        }
        __syncthreads();

        // S = Q K^T  (rows tm*4+i, keys tn*4+j)
        float s[4][4] = {};
        #pragma unroll 8
        for (int d = 0; d < 64; ++d) {
            float4 av = *(const float4*)&Qt[d][tm * 4];
            float4 bv = *(const float4*)&Kt[d][tn * 4];
            const float* ar = &av.x;
            const float* br = &bv.x;
            #pragma unroll
            for (int i = 0; i < 4; ++i)
                #pragma unroll
                for (int j = 0; j < 4; ++j)
                    s[i][j] += ar[i] * br[j];
        }
        if (s0 == q0) {   // causal mask, diagonal tile only
            #pragma unroll
            for (int i = 0; i < 4; ++i)
                #pragma unroll
                for (int j = 0; j < 4; ++j)
                    if (tn * 4 + j > tm * 4 + i) s[i][j] = -1e30f;
        }

        // online softmax per row (16-lane groups share a row set)
        #pragma unroll
        for (int i = 0; i < 4; ++i) {
            float pm = fmaxf(fmaxf(s[i][0], s[i][1]), fmaxf(s[i][2], s[i][3]));
            pm = fmaxf(pm, __shfl_xor(pm, 1));
            pm = fmaxf(pm, __shfl_xor(pm, 2));
            pm = fmaxf(pm, __shfl_xor(pm, 4));
            pm = fmaxf(pm, __shfl_xor(pm, 8));
            float mnew = fmaxf(mreg[i], pm);
            float c = __expf(mreg[i] - mnew);
            float ps = 0.f;
            #pragma unroll
            for (int j = 0; j < 4; ++j) { s[i][j] = __expf(s[i][j] - mnew); ps += s[i][j]; }
            ps += __shfl_xor(ps, 1);
            ps += __shfl_xor(ps, 2);
            ps += __shfl_xor(ps, 4);
            ps += __shfl_xor(ps, 8);
            lreg[i] = lreg[i] * c + ps;
            mreg[i] = mnew;
            #pragma unroll
            for (int j = 0; j < 4; ++j) acc[i][j] *= c;
            #pragma unroll
            for (int j = 0; j < 4; ++j) Pt[tn * 4 + j][tm * 4 + i] = s[i][j];
        }
        __syncthreads();

        // O += P V
        #pragma unroll 8
        for (int kk = 0; kk < 64; ++kk) {
            float4 av = *(const float4*)&Pt[kk][tm * 4];
            float4 bv = *(const float4*)&Vs[kk][tn * 4];
            const float* ar = &av.x;
            const float* br = &bv.x;
            #pragma unroll
            for (int i = 0; i < 4; ++i)
                #pragma unroll
                for (int j = 0; j < 4; ++j)
                    acc[i][j] += ar[i] * br[j];
        }
    }

    #pragma unroll
    for (int i = 0; i < 4; ++i) {
        float inv = 1.0f / lreg[i];
        float4 o = make_float4(acc[i][0] * inv, acc[i][1] * inv,
                               acc[i][2] * inv, acc[i][3] * inv);
        *(float4*)(out + ((size_t)(b * TT + q0 + tm * 4 + i)) * DD + h * HSS + tn * 4) = o;
    }
}

// ---------------- per-row -log-softmax[target]
__global__ __launch_bounds__(256)
void rowloss_kernel(const float* __restrict__ logits, const int* __restrict__ targets,
                    float* __restrict__ rowloss)
{
    __shared__ float red[256];
    const int row = blockIdx.x, tid = threadIdx.x;
    const float* lr = logits + (size_t)row * VV;
    float mx = -INFINITY;
    for (int i = tid; i < VV; i += 256) mx = fmaxf(mx, lr[i]);
    red[tid] = mx; __syncthreads();
    for (int s2 = 128; s2; s2 >>= 1) {
        if (tid < s2) red[tid] = fmaxf(red[tid], red[tid + s2]);
        __syncthreads();
    }
    mx = red[0]; __syncthreads();
    float s = 0.f;
    for (int i = tid; i < VV; i += 256) s += __expf(lr[i] - mx);
    red[tid] = s; __syncthreads();
    for (int s2 = 128; s2; s2 >>= 1) {
        if (tid < s2) red[tid] += red[tid + s2];
        __syncthreads();
    }
    if (tid == 0) rowloss[row] = -(lr[targets[row]] - mx - logf(red[0]));
}

__global__ __launch_bounds__(256)
void loss_finalize(const float* __restrict__ rowloss, float* __restrict__ out)
{
    __shared__ float red[256];
    float s = 0.f;
    for (int i = threadIdx.x; i < BB * TT; i += 256) s += rowloss[i];
    red[threadIdx.x] = s; __syncthreads();
    for (int s2 = 128; s2; s2 >>= 1) {
        if (threadIdx.x < s2) red[threadIdx.x] += red[threadIdx.x + s2];
        __syncthreads();
    }
    if (threadIdx.x == 0) out[0] = red[0] * (1.0f / (BB * TT));
}

extern "C" void kernel_launch(void* const* d_in, const int* in_sizes, int n_in,
                              void* d_out, int out_size, void* d_ws, size_t ws_size,
                              hipStream_t stream) {
    const int*   idx     = (const int*)  d_in[0];
    const int*   targets = (const int*)  d_in[1];
    const float* tok_emb = (const float*)d_in[2];
    const float* pos_emb = (const float*)d_in[3];
    const float* ln1_g   = (const float*)d_in[4];
    const float* ln1_b   = (const float*)d_in[5];
    const float* Wq      = (const float*)d_in[6];
    const float* Wk      = (const float*)d_in[7];
    const float* Wv      = (const float*)d_in[8];
    const float* Wo      = (const float*)d_in[9];
    const float* bo      = (const float*)d_in[10];
    const float* ln2_g   = (const float*)d_in[11];
    const float* ln2_b   = (const float*)d_in[12];
    const float* W1      = (const float*)d_in[13];
    const float* b1      = (const float*)d_in[14];
    const float* W2      = (const float*)d_in[15];
    const float* b2      = (const float*)d_in[16];
    const float* lnf_g   = (const float*)d_in[17];
    const float* lnf_b   = (const float*)d_in[18];
    const float* Wout    = (const float*)d_in[19];
    const float* bout    = (const float*)d_in[20];

    float* out    = (float*)d_out;
    float* logits = out + 1;                    // [B*T, V]

    float* ws = (float*)d_ws;
    const size_t ROW = (size_t)BB * TT;         // 4096
    float* x  = ws;                             // ROW*DD
    float* h  = x + ROW * DD;                   // ROW*DD  (also attnout)
    float* qb = h + ROW * DD;                   // ROW*DD
    float* kb = qb + ROW * DD;                  // ROW*DD
    float* vb = kb + ROW * DD;                  // ROW*DD
    float* ff = qb;                             // ROW*FF_ (aliases q,k,v + extra)
    float* rowloss = qb + ROW * FF_;            // ROW

    const size_t WQKV_L = (size_t)HH * DD * HSS;
    const size_t WO_L   = (size_t)DD * DD;
    const size_t W1_L   = (size_t)DD * FF_;
    const size_t W2_L   = (size_t)FF_ * DD;

    embed_kernel<<<ROW, 64, 0, stream>>>(idx, tok_emb, pos_emb, x);

    for (int l = 0; l < LL; ++l) {
        ln_kernel<<<ROW / 4, 256, 0, stream>>>(x, ln1_g + l * DD, ln1_b + l * DD, h);

        gemm_kernel<<<dim3(DD / 64, ROW / 64), 256, 0, stream>>>(
            h, DD, Wq + l * WQKV_L, HSS, DD * HSS, qb, DD, nullptr, nullptr, 0, DD, 0);
        gemm_kernel<<<dim3(DD / 64, ROW / 64), 256, 0, stream>>>(
            h, DD, Wk + l * WQKV_L, HSS, DD * HSS, kb, DD, nullptr, nullptr, 0, DD, 0);
        gemm_kernel<<<dim3(DD / 64, ROW / 64), 256, 0, stream>>>(
            h, DD, Wv + l * WQKV_L, HSS, DD * HSS, vb, DD, nullptr, nullptr, 0, DD, 0);

        attn_tile_kernel<<<dim3(TT / 64, BB * HH), 256, 0, stream>>>(qb, kb, vb, h);

        gemm_kernel<<<dim3(DD / 64, ROW / 64), 256, 0, stream>>>(
            h, DD, Wo + l * WO_L, DD, 0, x, DD, bo + l * DD, x, DD, DD, 0);

        ln_kernel<<<ROW / 4, 256, 0, stream>>>(x, ln2_g + l * DD, ln2_b + l * DD, h);

        gemm_kernel<<<dim3(FF_ / 64, ROW / 64), 256, 0, stream>>>(
            h, DD, W1 + l * W1_L, FF_, 0, ff, FF_, b1 + l * FF_, nullptr, 0, DD, 1);

        gemm_kernel<<<dim3(DD / 64, ROW / 64), 256, 0, stream>>>(
            ff, FF_, W2 + l * W2_L, DD, 0, x, DD, b2 + l * DD, x, DD, FF_, 0);
    }

    ln_kernel<<<ROW / 4, 256, 0, stream>>>(x, lnf_g, lnf_b, h);

    gemm_kernel<<<dim3(VV / 64, ROW / 64), 256, 0, stream>>>(
        h, DD, Wout, VV, 0, logits, VV, bout, nullptr, 0, DD, 0);

    rowloss_kernel<<<ROW, 256, 0, stream>>>(logits, targets, rowloss);
    loss_finalize<<<1, 256, 0, stream>>>(rowloss, out);
}

// Round 4
// 2599.065 us; speedup vs baseline: 5.6648x; 1.9410x over previous
//
#include <hip/hip_runtime.h>
#include <hip/hip_bf16.h>
#include <math.h>

#define TT 2048
#define BB 2
#define VV 32000
#define DD 512
#define HH 8
#define HSS 64
#define LL 4
#define FF_ 2048

using bf16x8 = __attribute__((ext_vector_type(8))) short;
using floatx4 = __attribute__((ext_vector_type(4))) float;

__device__ __forceinline__ ushort f2bf(float f) {
    __hip_bfloat16 b = __float2bfloat16(f);
    return *reinterpret_cast<ushort*>(&b);
}
__device__ __forceinline__ float bf2f(ushort u) {
    union { unsigned int i; float f; } x; x.i = ((unsigned int)u) << 16; return x.f;
}
__device__ __forceinline__ void gload16(const void* g, void* l) {
    __builtin_amdgcn_global_load_lds(
        (const __attribute__((address_space(1))) void*)g,
        (__attribute__((address_space(3))) void*)l, 16, 0, 0);
}

// ---------------- embedding: x[b,t,:] = tok_emb[idx[b,t],:] + pos_emb[t,:]
__global__ __launch_bounds__(64)
void embed_kernel(const int* __restrict__ idx, const float* __restrict__ tok,
                  const float* __restrict__ pos, float* __restrict__ x)
{
    int row = blockIdx.x;
    int t = row & (TT - 1);
    int tokid = idx[row];
    int lane = threadIdx.x;
    const float4* tp = (const float4*)(tok + (size_t)tokid * DD);
    const float4* pp = (const float4*)(pos + (size_t)t * DD);
    float4* xp = (float4*)(x + (size_t)row * DD);
    int i0 = lane * 2;
    float4 a = tp[i0],   b4 = pp[i0];
    float4 c = tp[i0+1], d4 = pp[i0+1];
    xp[i0]   = make_float4(a.x + b4.x, a.y + b4.y, a.z + b4.z, a.w + b4.w);
    xp[i0+1] = make_float4(c.x + d4.x, c.y + d4.y, c.z + d4.z, c.w + d4.w);
}

// ---------------- layernorm: wave per row, bf16 output
__global__ __launch_bounds__(256)
void ln_kernel(const float* __restrict__ x, const float* __restrict__ g,
               const float* __restrict__ b, ushort* __restrict__ out)
{
    int wave = threadIdx.x >> 6;
    int lane = threadIdx.x & 63;
    int row  = blockIdx.x * 4 + wave;
    const float* xr = x + (size_t)row * DD;
    float4 v0 = *(const float4*)(xr + lane * 8);
    float4 v1 = *(const float4*)(xr + lane * 8 + 4);
    float s = v0.x + v0.y + v0.z + v0.w + v1.x + v1.y + v1.z + v1.w;
    float q = v0.x*v0.x + v0.y*v0.y + v0.z*v0.z + v0.w*v0.w
            + v1.x*v1.x + v1.y*v1.y + v1.z*v1.z + v1.w*v1.w;
    #pragma unroll
    for (int off = 32; off; off >>= 1) {
        s += __shfl_xor(s, off);
        q += __shfl_xor(q, off);
    }
    float mu  = s * (1.0f / DD);
    float var = q * (1.0f / DD) - mu * mu;
    float rs  = rsqrtf(var + 1e-5f);
    float4 g0 = *(const float4*)(g + lane * 8);
    float4 g1 = *(const float4*)(g + lane * 8 + 4);
    float4 b0 = *(const float4*)(b + lane * 8);
    float4 b1 = *(const float4*)(b + lane * 8 + 4);
    union { ushort u[8]; uint4 v; } pk;
    pk.u[0] = f2bf((v0.x - mu) * rs * g0.x + b0.x);
    pk.u[1] = f2bf((v0.y - mu) * rs * g0.y + b0.y);
    pk.u[2] = f2bf((v0.z - mu) * rs * g0.z + b0.z);
    pk.u[3] = f2bf((v0.w - mu) * rs * g0.w + b0.w);
    pk.u[4] = f2bf((v1.x - mu) * rs * g1.x + b1.x);
    pk.u[5] = f2bf((v1.y - mu) * rs * g1.y + b1.y);
    pk.u[6] = f2bf((v1.z - mu) * rs * g1.z + b1.z);
    pk.u[7] = f2bf((v1.w - mu) * rs * g1.w + b1.w);
    *(uint4*)(out + (size_t)row * DD + lane * 8) = pk.v;
}

// ---------------- generic transpose+convert: in [K][N] f32 -> out [N][K] bf16
// grid (N/64, K/64, nz)
__global__ __launch_bounds__(256)
void transpose_cvt(const float* __restrict__ in, ushort* __restrict__ out,
                   int N, int K, long inStrideZ, long outStrideZ)
{
    __shared__ float t[64][65];
    in  += (size_t)blockIdx.z * inStrideZ;
    out += (size_t)blockIdx.z * outStrideZ;
    const int n0 = blockIdx.x * 64, k0 = blockIdx.y * 64;
    const int r = threadIdx.x >> 2;
    const int c = (threadIdx.x & 3) * 16;
    #pragma unroll
    for (int j = 0; j < 16; j += 4) {
        float4 v = *(const float4*)&in[(size_t)(k0 + r) * N + n0 + c + j];
        t[r][c + j + 0] = v.x; t[r][c + j + 1] = v.y;
        t[r][c + j + 2] = v.z; t[r][c + j + 3] = v.w;
    }
    __syncthreads();
    union { ushort u[8]; uint4 v; } pk;
    ushort* orow = out + (size_t)(n0 + r) * K + k0 + c;
    #pragma unroll
    for (int half = 0; half < 2; ++half) {
        #pragma unroll
        for (int j = 0; j < 8; ++j) pk.u[j] = f2bf(t[c + half * 8 + j][r]);
        *(uint4*)(orow + half * 8) = pk.v;
    }
}

// ---------------- QKV weights: [L][H][D][HS] f32 -> fused [L][1536][512] bf16
// out row n = sel*512 + h*64 + e holds W{q,k,v}[l][h][:,e]. grid (8, 96)
__global__ __launch_bounds__(256)
void qkv_transpose(const float* __restrict__ Wq, const float* __restrict__ Wk,
                   const float* __restrict__ Wv, ushort* __restrict__ out)
{
    __shared__ float t[64][65];
    const int z = blockIdx.y;
    const int sel = z >> 5, l = (z >> 3) & 3, h = z & 7;
    const float* in = (sel == 0 ? Wq : sel == 1 ? Wk : Wv)
                      + (size_t)l * (HH * DD * HSS) + (size_t)h * (DD * HSS);
    ushort* ob = out + (size_t)l * (3 * DD * DD) + (size_t)sel * (DD * DD)
                     + (size_t)h * (HSS * DD);
    const int d0 = blockIdx.x * 64;
    const int r = threadIdx.x >> 2;
    const int c = (threadIdx.x & 3) * 16;
    #pragma unroll
    for (int j = 0; j < 16; j += 4) {
        float4 v = *(const float4*)&in[(size_t)(d0 + r) * HSS + c + j];
        t[r][c + j + 0] = v.x; t[r][c + j + 1] = v.y;
        t[r][c + j + 2] = v.z; t[r][c + j + 3] = v.w;
    }
    __syncthreads();
    union { ushort u[8]; uint4 v; } pk;
    ushort* orow = ob + (size_t)r * DD + d0 + c;   // out[e=r][d0+c..]
    #pragma unroll
    for (int half = 0; half < 2; ++half) {
        #pragma unroll
        for (int j = 0; j < 8; ++j) pk.u[j] = f2bf(t[c + half * 8 + j][r]);
        *(uint4*)(orow + half * 8) = pk.v;
    }
}

// ---------------- bf16 MFMA GEMM: C[M,N] = A[M,K] @ Bt[N,K]^T (+bias)(+resid)(relu)
// 128x128 tile, BK=64, 4 waves 2x2, fragment-major LDS via global_load_lds.
__global__ __launch_bounds__(256)
void mfma_gemm(const ushort* __restrict__ A, int lda,
               const ushort* __restrict__ Bt, int ldb,
               float* __restrict__ Cf, ushort* __restrict__ Cbf, int ldc,
               const float* __restrict__ bias,
               const float* __restrict__ resid, int ldres,
               int K, int relu)
{
    __shared__ ushort As[16 * 512];   // 16 chunks: [wm|mi|kh][lane][8]
    __shared__ ushort Bs[16 * 512];
    const int m0 = blockIdx.y << 7, n0 = blockIdx.x << 7;
    const int tid = threadIdx.x, w = tid >> 6, lane = tid & 63;
    const int wm = w >> 1, wn = w & 1;
    const int l15 = lane & 15, lk = lane >> 4;

    floatx4 acc[4][4] = {};

    for (int k0 = 0; k0 < K; k0 += 64) {
        #pragma unroll
        for (int i = 0; i < 4; ++i) {
            int c = 4 * w + i;
            int cg = c >> 3, cmi = (c >> 1) & 3, ckh = c & 1;
            const ushort* ga = A + (size_t)(m0 + cg * 64 + cmi * 16 + l15) * lda
                                 + k0 + lk * 8 + ckh * 32;
            gload16(ga, &As[c * 512]);
            const ushort* gb = Bt + (size_t)(n0 + cg * 64 + cmi * 16 + l15) * ldb
                                  + k0 + lk * 8 + ckh * 32;
            gload16(gb, &Bs[c * 512]);
        }
        __syncthreads();
        #pragma unroll
        for (int kh = 0; kh < 2; ++kh) {
            bf16x8 af[4], bfr[4];
            #pragma unroll
            for (int mi = 0; mi < 4; ++mi)
                af[mi] = *(const bf16x8*)&As[((wm * 8 + mi * 2 + kh) * 64 + lane) * 8];
            #pragma unroll
            for (int ni = 0; ni < 4; ++ni)
                bfr[ni] = *(const bf16x8*)&Bs[((wn * 8 + ni * 2 + kh) * 64 + lane) * 8];
            #pragma unroll
            for (int mi = 0; mi < 4; ++mi)
                #pragma unroll
                for (int ni = 0; ni < 4; ++ni)
                    acc[mi][ni] = __builtin_amdgcn_mfma_f32_16x16x32_bf16(
                        af[mi], bfr[ni], acc[mi][ni], 0, 0, 0);
        }
        __syncthreads();
    }

    #pragma unroll
    for (int mi = 0; mi < 4; ++mi) {
        #pragma unroll
        for (int r = 0; r < 4; ++r) {
            int grow = m0 + wm * 64 + mi * 16 + lk * 4 + r;
            #pragma unroll
            for (int ni = 0; ni < 4; ++ni) {
                int gcol = n0 + wn * 64 + ni * 16 + l15;
                float v = acc[mi][ni][r];
                if (bias)  v += bias[gcol];
                if (resid) v += resid[(size_t)grow * ldres + gcol];
                if (relu)  v = fmaxf(v, 0.0f);
                if (Cbf) Cbf[(size_t)grow * ldc + gcol] = f2bf(v);
                else     Cf [(size_t)grow * ldc + gcol] = v;
            }
        }
    }
}

// ---------------- tiled flash attention (fp32 math, bf16 I/O)
// qkv: [B*T][1536] bf16 (q|k|v each 512 = 8 heads x 64). out: [B*T][512] bf16.
__global__ __launch_bounds__(256)
void attn_tile_kernel(const ushort* __restrict__ qkv, ushort* __restrict__ out)
{
    __shared__ float Qt[64][68];
    __shared__ float Kt[64][68];
    __shared__ float Vs[64][68];
    __shared__ float Pt[64][68];

    const int z = blockIdx.y, b = z >> 3, h = z & 7;
    const int q0 = blockIdx.x << 6;
    const int tid = threadIdx.x;
    const int tn = tid & 15, tm = tid >> 4;
    const int lrow = tid >> 2;
    const int ld0  = (tid & 3) << 4;
    const float scale = 0.04419417382415922f;  // 1/sqrt(512)

    {
        const ushort* qp = qkv + ((size_t)(b * TT + q0 + lrow)) * 1536 + h * HSS + ld0;
        uint4 u0 = *(const uint4*)qp;
        uint4 u1 = *(const uint4*)(qp + 8);
        const ushort* s0 = (const ushort*)&u0;
        const ushort* s1 = (const ushort*)&u1;
        #pragma unroll
        for (int j = 0; j < 8; ++j) {
            Qt[ld0 + j][lrow]     = bf2f(s0[j]) * scale;
            Qt[ld0 + 8 + j][lrow] = bf2f(s1[j]) * scale;
        }
    }

    float acc[4][4] = {};
    float mreg[4] = {-1e30f, -1e30f, -1e30f, -1e30f};
    float lreg[4] = {};

    for (int s0i = 0; s0i <= q0; s0i += 64) {
        __syncthreads();
        {
            const ushort* kp = qkv + ((size_t)(b * TT + s0i + lrow)) * 1536 + 512 + h * HSS + ld0;
            const ushort* vp = kp + 512;
            uint4 ku0 = *(const uint4*)kp;
            uint4 ku1 = *(const uint4*)(kp + 8);
            uint4 vu0 = *(const uint4*)vp;
            uint4 vu1 = *(const uint4*)(vp + 8);
            const ushort* k0s = (const ushort*)&ku0;
            const ushort* k1s = (const ushort*)&ku1;
            const ushort* v0s = (const ushort*)&vu0;
            const ushort* v1s = (const ushort*)&vu1;
            #pragma unroll
            for (int j = 0; j < 8; ++j) {
                Kt[ld0 + j][lrow]     = bf2f(k0s[j]);
                Kt[ld0 + 8 + j][lrow] = bf2f(k1s[j]);
                Vs[lrow][ld0 + j]     = bf2f(v0s[j]);
                Vs[lrow][ld0 + 8 + j] = bf2f(v1s[j]);
            }
        }
        __syncthreads();

        float s[4][4] = {};
        #pragma unroll 8
        for (int d = 0; d < 64; ++d) {
            float4 av = *(const float4*)&Qt[d][tm * 4];
            float4 bv = *(const float4*)&Kt[d][tn * 4];
            const float* ar = &av.x;
            const float* br = &bv.x;
            #pragma unroll
            for (int i = 0; i < 4; ++i)
                #pragma unroll
                for (int j = 0; j < 4; ++j)
                    s[i][j] += ar[i] * br[j];
        }
        if (s0i == q0) {
            #pragma unroll
            for (int i = 0; i < 4; ++i)
                #pragma unroll
                for (int j = 0; j < 4; ++j)
                    if (tn * 4 + j > tm * 4 + i) s[i][j] = -1e30f;
        }

        #pragma unroll
        for (int i = 0; i < 4; ++i) {
            float pm = fmaxf(fmaxf(s[i][0], s[i][1]), fmaxf(s[i][2], s[i][3]));
            pm = fmaxf(pm, __shfl_xor(pm, 1));
            pm = fmaxf(pm, __shfl_xor(pm, 2));
            pm = fmaxf(pm, __shfl_xor(pm, 4));
            pm = fmaxf(pm, __shfl_xor(pm, 8));
            float mnew = fmaxf(mreg[i], pm);
            float c = __expf(mreg[i] - mnew);
            float ps = 0.f;
            #pragma unroll
            for (int j = 0; j < 4; ++j) { s[i][j] = __expf(s[i][j] - mnew); ps += s[i][j]; }
            ps += __shfl_xor(ps, 1);
            ps += __shfl_xor(ps, 2);
            ps += __shfl_xor(ps, 4);
            ps += __shfl_xor(ps, 8);
            lreg[i] = lreg[i] * c + ps;
            mreg[i] = mnew;
            #pragma unroll
            for (int j = 0; j < 4; ++j) acc[i][j] *= c;
            #pragma unroll
            for (int j = 0; j < 4; ++j) Pt[tn * 4 + j][tm * 4 + i] = s[i][j];
        }
        __syncthreads();

        #pragma unroll 8
        for (int kk = 0; kk < 64; ++kk) {
            float4 av = *(const float4*)&Pt[kk][tm * 4];
            float4 bv = *(const float4*)&Vs[kk][tn * 4];
            const float* ar = &av.x;
            const float* br = &bv.x;
            #pragma unroll
            for (int i = 0; i < 4; ++i)
                #pragma unroll
                for (int j = 0; j < 4; ++j)
                    acc[i][j] += ar[i] * br[j];
        }
    }

    #pragma unroll
    for (int i = 0; i < 4; ++i) {
        float inv = 1.0f / lreg[i];
        ushort4 o;
        o.x = f2bf(acc[i][0] * inv);
        o.y = f2bf(acc[i][1] * inv);
        o.z = f2bf(acc[i][2] * inv);
        o.w = f2bf(acc[i][3] * inv);
        *(ushort4*)(out + ((size_t)(b * TT + q0 + tm * 4 + i)) * DD + h * HSS + tn * 4) = o;
    }
}

// ---------------- per-row -log-softmax[target]
__global__ __launch_bounds__(256)
void rowloss_kernel(const float* __restrict__ logits, const int* __restrict__ targets,
                    float* __restrict__ rowloss)
{
    __shared__ float red[256];
    const int row = blockIdx.x, tid = threadIdx.x;
    const float* lr = logits + (size_t)row * VV;
    float mx = -INFINITY;
    for (int i = tid; i < VV; i += 256) mx = fmaxf(mx, lr[i]);
    red[tid] = mx; __syncthreads();
    for (int s2 = 128; s2; s2 >>= 1) {
        if (tid < s2) red[tid] = fmaxf(red[tid], red[tid + s2]);
        __syncthreads();
    }
    mx = red[0]; __syncthreads();
    float s = 0.f;
    for (int i = tid; i < VV; i += 256) s += __expf(lr[i] - mx);
    red[tid] = s; __syncthreads();
    for (int s2 = 128; s2; s2 >>= 1) {
        if (tid < s2) red[tid] += red[tid + s2];
        __syncthreads();
    }
    if (tid == 0) rowloss[row] = -(lr[targets[row]] - mx - logf(red[0]));
}

__global__ __launch_bounds__(256)
void loss_finalize(const float* __restrict__ rowloss, float* __restrict__ out)
{
    __shared__ float red[256];
    float s = 0.f;
    for (int i = threadIdx.x; i < BB * TT; i += 256) s += rowloss[i];
    red[threadIdx.x] = s; __syncthreads();
    for (int s2 = 128; s2; s2 >>= 1) {
        if (threadIdx.x < s2) red[threadIdx.x] += red[threadIdx.x + s2];
        __syncthreads();
    }
    if (threadIdx.x == 0) out[0] = red[0] * (1.0f / (BB * TT));
}

extern "C" void kernel_launch(void* const* d_in, const int* in_sizes, int n_in,
                              void* d_out, int out_size, void* d_ws, size_t ws_size,
                              hipStream_t stream) {
    const int*   idx     = (const int*)  d_in[0];
    const int*   targets = (const int*)  d_in[1];
    const float* tok_emb = (const float*)d_in[2];
    const float* pos_emb = (const float*)d_in[3];
    const float* ln1_g   = (const float*)d_in[4];
    const float* ln1_b   = (const float*)d_in[5];
    const float* Wq      = (const float*)d_in[6];
    const float* Wk      = (const float*)d_in[7];
    const float* Wv      = (const float*)d_in[8];
    const float* Wo      = (const float*)d_in[9];
    const float* bo      = (const float*)d_in[10];
    const float* ln2_g   = (const float*)d_in[11];
    const float* ln2_b   = (const float*)d_in[12];
    const float* W1      = (const float*)d_in[13];
    const float* b1      = (const float*)d_in[14];
    const float* W2      = (const float*)d_in[15];
    const float* b2      = (const float*)d_in[16];
    const float* lnf_g   = (const float*)d_in[17];
    const float* lnf_b   = (const float*)d_in[18];
    const float* Wout    = (const float*)d_in[19];
    const float* bout    = (const float*)d_in[20];

    float* outf   = (float*)d_out;
    float* logits = outf + 1;                   // [B*T, V] fp32

    const size_t ROW = (size_t)BB * TT;         // 4096

    // ---- d_ws: x (fp32) | h_bf | Wout^T (bf16) | rowloss  (~45 MB)
    float*  x     = (float*)d_ws;
    ushort* h_bf  = (ushort*)(x + ROW * DD);
    ushort* Woutt = h_bf + ROW * DD;
    float*  rowloss = (float*)(Woutt + (size_t)VV * DD);

    // ---- scratch inside the (dead-until-final) logits region of d_out
    ushort* sc     = (ushort*)(outf + 8);       // 32B-aligned
    ushort* qkv_bf = sc;                        // ROW*1536
    ushort* ff_bf  = qkv_bf + ROW * 1536;       // ROW*2048
    ushort* Wqkvt  = ff_bf + ROW * FF_;         // L*1536*512
    ushort* Wot    = Wqkvt + (size_t)LL * 1536 * DD;   // L*512*512
    ushort* W1t    = Wot   + (size_t)LL * DD * DD;     // L*2048*512
    ushort* W2t    = W1t   + (size_t)LL * FF_ * DD;    // L*512*2048

    // ---- weight transpose+convert (bf16)
    qkv_transpose<<<dim3(8, 96), 256, 0, stream>>>(Wq, Wk, Wv, Wqkvt);
    transpose_cvt<<<dim3(8, 8, LL),  256, 0, stream>>>(Wo,   Wot,   DD,  DD,  (long)DD*DD,   (long)DD*DD);
    transpose_cvt<<<dim3(32, 8, LL), 256, 0, stream>>>(W1,   W1t,   FF_, DD,  (long)DD*FF_,  (long)DD*FF_);
    transpose_cvt<<<dim3(8, 32, LL), 256, 0, stream>>>(W2,   W2t,   DD,  FF_, (long)FF_*DD,  (long)FF_*DD);
    transpose_cvt<<<dim3(500, 8, 1), 256, 0, stream>>>(Wout, Woutt, VV,  DD,  0, 0);

    embed_kernel<<<ROW, 64, 0, stream>>>(idx, tok_emb, pos_emb, x);

    for (int l = 0; l < LL; ++l) {
        ln_kernel<<<ROW / 4, 256, 0, stream>>>(x, ln1_g + l * DD, ln1_b + l * DD, h_bf);

        // qkv = h @ [Wq|Wk|Wv]^T  -> bf16 [4096][1536]
        mfma_gemm<<<dim3(1536 / 128, ROW / 128), 256, 0, stream>>>(
            h_bf, DD, Wqkvt + (size_t)l * 1536 * DD, DD,
            nullptr, qkv_bf, 1536, nullptr, nullptr, 0, DD, 0);

        attn_tile_kernel<<<dim3(TT / 64, BB * HH), 256, 0, stream>>>(qkv_bf, h_bf);

        // x = x + attn @ Wo + bo
        mfma_gemm<<<dim3(DD / 128, ROW / 128), 256, 0, stream>>>(
            h_bf, DD, Wot + (size_t)l * DD * DD, DD,
            x, nullptr, DD, bo + l * DD, x, DD, DD, 0);

        ln_kernel<<<ROW / 4, 256, 0, stream>>>(x, ln2_g + l * DD, ln2_b + l * DD, h_bf);

        // ff = relu(h @ W1 + b1) -> bf16
        mfma_gemm<<<dim3(FF_ / 128, ROW / 128), 256, 0, stream>>>(
            h_bf, DD, W1t + (size_t)l * FF_ * DD, DD,
            nullptr, ff_bf, FF_, b1 + l * FF_, nullptr, 0, DD, 1);

        // x = x + ff @ W2 + b2
        mfma_gemm<<<dim3(DD / 128, ROW / 128), 256, 0, stream>>>(
            ff_bf, FF_, W2t + (size_t)l * DD * FF_, FF_,
            x, nullptr, DD, b2 + l * DD, x, DD, FF_, 0);
    }

    ln_kernel<<<ROW / 4, 256, 0, stream>>>(x, lnf_g, lnf_b, h_bf);

    // logits = h @ Wout + bout (fp32 into d_out+1; reads only d_ws/d_in)
    mfma_gemm<<<dim3(VV / 128, ROW / 128), 256, 0, stream>>>(
        h_bf, DD, Woutt, DD,
        logits, nullptr, VV, bout, nullptr, 0, DD, 0);

    rowloss_kernel<<<ROW, 256, 0, stream>>>(logits, targets, rowloss);
    loss_finalize<<<1, 256, 0, stream>>>(rowloss, outf);
}

// Round 5
// 1995.736 us; speedup vs baseline: 7.3773x; 1.3023x over previous
//
#include <hip/hip_runtime.h>
#include <hip/hip_bf16.h>
#include <math.h>

#define TT 2048
#define BB 2
#define VV 32000
#define DD 512
#define HH 8
#define HSS 64
#define LL 4
#define FF_ 2048

using bf16x8 = __attribute__((ext_vector_type(8))) short;
using floatx4 = __attribute__((ext_vector_type(4))) float;

__device__ __forceinline__ ushort f2bf(float f) {
    __hip_bfloat16 b = __float2bfloat16(f);
    return *reinterpret_cast<ushort*>(&b);
}
__device__ __forceinline__ float bf2f(ushort u) {
    union { unsigned int i; float f; } x; x.i = ((unsigned int)u) << 16; return x.f;
}
__device__ __forceinline__ void gload16(const void* g, void* l) {
    __builtin_amdgcn_global_load_lds(
        (const __attribute__((address_space(1))) void*)g,
        (__attribute__((address_space(3))) void*)l, 16, 0, 0);
}

// ---------------- embedding
__global__ __launch_bounds__(64)
void embed_kernel(const int* __restrict__ idx, const float* __restrict__ tok,
                  const float* __restrict__ pos, float* __restrict__ x)
{
    int row = blockIdx.x;
    int t = row & (TT - 1);
    int tokid = idx[row];
    int lane = threadIdx.x;
    const float4* tp = (const float4*)(tok + (size_t)tokid * DD);
    const float4* pp = (const float4*)(pos + (size_t)t * DD);
    float4* xp = (float4*)(x + (size_t)row * DD);
    int i0 = lane * 2;
    float4 a = tp[i0],   b4 = pp[i0];
    float4 c = tp[i0+1], d4 = pp[i0+1];
    xp[i0]   = make_float4(a.x + b4.x, a.y + b4.y, a.z + b4.z, a.w + b4.w);
    xp[i0+1] = make_float4(c.x + d4.x, c.y + d4.y, c.z + d4.z, c.w + d4.w);
}

// ---------------- layernorm -> bf16
__global__ __launch_bounds__(256)
void ln_kernel(const float* __restrict__ x, const float* __restrict__ g,
               const float* __restrict__ b, ushort* __restrict__ out)
{
    int wave = threadIdx.x >> 6;
    int lane = threadIdx.x & 63;
    int row  = blockIdx.x * 4 + wave;
    const float* xr = x + (size_t)row * DD;
    float4 v0 = *(const float4*)(xr + lane * 8);
    float4 v1 = *(const float4*)(xr + lane * 8 + 4);
    float s = v0.x + v0.y + v0.z + v0.w + v1.x + v1.y + v1.z + v1.w;
    float q = v0.x*v0.x + v0.y*v0.y + v0.z*v0.z + v0.w*v0.w
            + v1.x*v1.x + v1.y*v1.y + v1.z*v1.z + v1.w*v1.w;
    #pragma unroll
    for (int off = 32; off; off >>= 1) {
        s += __shfl_xor(s, off);
        q += __shfl_xor(q, off);
    }
    float mu  = s * (1.0f / DD);
    float var = q * (1.0f / DD) - mu * mu;
    float rs  = rsqrtf(var + 1e-5f);
    float4 g0 = *(const float4*)(g + lane * 8);
    float4 g1 = *(const float4*)(g + lane * 8 + 4);
    float4 b0 = *(const float4*)(b + lane * 8);
    float4 b1 = *(const float4*)(b + lane * 8 + 4);
    union { ushort u[8]; uint4 v; } pk;
    pk.u[0] = f2bf((v0.x - mu) * rs * g0.x + b0.x);
    pk.u[1] = f2bf((v0.y - mu) * rs * g0.y + b0.y);
    pk.u[2] = f2bf((v0.z - mu) * rs * g0.z + b0.z);
    pk.u[3] = f2bf((v0.w - mu) * rs * g0.w + b0.w);
    pk.u[4] = f2bf((v1.x - mu) * rs * g1.x + b1.x);
    pk.u[5] = f2bf((v1.y - mu) * rs * g1.y + b1.y);
    pk.u[6] = f2bf((v1.z - mu) * rs * g1.z + b1.z);
    pk.u[7] = f2bf((v1.w - mu) * rs * g1.w + b1.w);
    *(uint4*)(out + (size_t)row * DD + lane * 8) = pk.v;
}

// ---------------- transpose+convert: in [K][N] f32 -> out [N][K] bf16
__global__ __launch_bounds__(256)
void transpose_cvt(const float* __restrict__ in, ushort* __restrict__ out,
                   int N, int K, long inStrideZ, long outStrideZ)
{
    __shared__ float t[64][65];
    in  += (size_t)blockIdx.z * inStrideZ;
    out += (size_t)blockIdx.z * outStrideZ;
    const int n0 = blockIdx.x * 64, k0 = blockIdx.y * 64;
    const int r = threadIdx.x >> 2;
    const int c = (threadIdx.x & 3) * 16;
    #pragma unroll
    for (int j = 0; j < 16; j += 4) {
        float4 v = *(const float4*)&in[(size_t)(k0 + r) * N + n0 + c + j];
        t[r][c + j + 0] = v.x; t[r][c + j + 1] = v.y;
        t[r][c + j + 2] = v.z; t[r][c + j + 3] = v.w;
    }
    __syncthreads();
    union { ushort u[8]; uint4 v; } pk;
    ushort* orow = out + (size_t)(n0 + r) * K + k0 + c;
    #pragma unroll
    for (int half = 0; half < 2; ++half) {
        #pragma unroll
        for (int j = 0; j < 8; ++j) pk.u[j] = f2bf(t[c + half * 8 + j][r]);
        *(uint4*)(orow + half * 8) = pk.v;
    }
}

// ---------------- QKV weights -> fused [L][1536][512] bf16
__global__ __launch_bounds__(256)
void qkv_transpose(const float* __restrict__ Wq, const float* __restrict__ Wk,
                   const float* __restrict__ Wv, ushort* __restrict__ out)
{
    __shared__ float t[64][65];
    const int z = blockIdx.y;
    const int sel = z >> 5, l = (z >> 3) & 3, h = z & 7;
    const float* in = (sel == 0 ? Wq : sel == 1 ? Wk : Wv)
                      + (size_t)l * (HH * DD * HSS) + (size_t)h * (DD * HSS);
    ushort* ob = out + (size_t)l * (3 * DD * DD) + (size_t)sel * (DD * DD)
                     + (size_t)h * (HSS * DD);
    const int d0 = blockIdx.x * 64;
    const int r = threadIdx.x >> 2;
    const int c = (threadIdx.x & 3) * 16;
    #pragma unroll
    for (int j = 0; j < 16; j += 4) {
        float4 v = *(const float4*)&in[(size_t)(d0 + r) * HSS + c + j];
        t[r][c + j + 0] = v.x; t[r][c + j + 1] = v.y;
        t[r][c + j + 2] = v.z; t[r][c + j + 3] = v.w;
    }
    __syncthreads();
    union { ushort u[8]; uint4 v; } pk;
    ushort* orow = ob + (size_t)r * DD + d0 + c;
    #pragma unroll
    for (int half = 0; half < 2; ++half) {
        #pragma unroll
        for (int j = 0; j < 8; ++j) pk.u[j] = f2bf(t[c + half * 8 + j][r]);
        *(uint4*)(orow + half * 8) = pk.v;
    }
}

// ---------------- bf16 MFMA GEMM: C = A[M,K] @ Bt[N,K]^T (+bias)(+resid)(relu)
// mswap: blockIdx.x indexes M (fast) so consecutive blocks share a B-panel.
__global__ __launch_bounds__(256)
void mfma_gemm(const ushort* __restrict__ A, int lda,
               const ushort* __restrict__ Bt, int ldb,
               float* __restrict__ Cf, ushort* __restrict__ Cbf, int ldc,
               const float* __restrict__ bias,
               const float* __restrict__ resid, int ldres,
               int K, int relu, int mswap)
{
    __shared__ ushort As[16 * 512];
    __shared__ ushort Bs[16 * 512];
    const int bxx = mswap ? blockIdx.y : blockIdx.x;
    const int byy = mswap ? blockIdx.x : blockIdx.y;
    const int m0 = byy << 7, n0 = bxx << 7;
    const int tid = threadIdx.x, w = tid >> 6, lane = tid & 63;
    const int wm = w >> 1, wn = w & 1;
    const int l15 = lane & 15, lk = lane >> 4;

    floatx4 acc[4][4] = {};

    for (int k0 = 0; k0 < K; k0 += 64) {
        #pragma unroll
        for (int i = 0; i < 4; ++i) {
            int c = 4 * w + i;
            int cg = c >> 3, cmi = (c >> 1) & 3, ckh = c & 1;
            const ushort* ga = A + (size_t)(m0 + cg * 64 + cmi * 16 + l15) * lda
                                 + k0 + lk * 8 + ckh * 32;
            gload16(ga, &As[c * 512]);
            const ushort* gb = Bt + (size_t)(n0 + cg * 64 + cmi * 16 + l15) * ldb
                                  + k0 + lk * 8 + ckh * 32;
            gload16(gb, &Bs[c * 512]);
        }
        __syncthreads();
        #pragma unroll
        for (int kh = 0; kh < 2; ++kh) {
            bf16x8 af[4], bfr[4];
            #pragma unroll
            for (int mi = 0; mi < 4; ++mi)
                af[mi] = *(const bf16x8*)&As[((wm * 8 + mi * 2 + kh) * 64 + lane) * 8];
            #pragma unroll
            for (int ni = 0; ni < 4; ++ni)
                bfr[ni] = *(const bf16x8*)&Bs[((wn * 8 + ni * 2 + kh) * 64 + lane) * 8];
            #pragma unroll
            for (int mi = 0; mi < 4; ++mi)
                #pragma unroll
                for (int ni = 0; ni < 4; ++ni)
                    acc[mi][ni] = __builtin_amdgcn_mfma_f32_16x16x32_bf16(
                        af[mi], bfr[ni], acc[mi][ni], 0, 0, 0);
        }
        __syncthreads();
    }

    #pragma unroll
    for (int mi = 0; mi < 4; ++mi) {
        #pragma unroll
        for (int r = 0; r < 4; ++r) {
            int grow = m0 + wm * 64 + mi * 16 + lk * 4 + r;
            #pragma unroll
            for (int ni = 0; ni < 4; ++ni) {
                int gcol = n0 + wn * 64 + ni * 16 + l15;
                float v = acc[mi][ni][r];
                if (bias)  v += bias[gcol];
                if (resid) v += resid[(size_t)grow * ldres + gcol];
                if (relu)  v = fmaxf(v, 0.0f);
                if (Cbf) Cbf[(size_t)grow * ldc + gcol] = f2bf(v);
                else     Cf [(size_t)grow * ldc + gcol] = v;
            }
        }
    }
}

// ---------------- MFMA flash attention (bf16 MFMA, fp32 softmax)
// qkv: [B*T][1536] bf16 (q|k|v). One block per (b,h,64-q-tile), 4 waves.
// Wave w owns q-rows 16w..16w+15. scale = 1/sqrt(512) per reference.
__global__ __launch_bounds__(256)
void attn_mfma_kernel(const ushort* __restrict__ qkv, ushort* __restrict__ out)
{
    __shared__ ushort Vt[64][72];   // Vt[d][key]
    __shared__ ushort Pl[64][72];   // P[q_local][key]

    const int z = blockIdx.y, b = z >> 3, h = z & 7;
    const int q0 = blockIdx.x << 6;
    const int tid = threadIdx.x;
    const int w = tid >> 6, lane = tid & 63;
    const int l15 = lane & 15, g = lane >> 4;
    const float scale = 0.04419417382415922f;  // 1/sqrt(512)

    const int vkey = tid & 63, vd0 = (tid >> 6) * 16;   // V-stage mapping

    // Q fragments (A-layout: row=l15, k=d=g*8 (+kh*32)), held in registers
    bf16x8 qf0, qf1;
    {
        const ushort* qp = qkv + ((size_t)(b * TT + q0 + 16 * w + l15)) * 1536
                               + h * HSS + g * 8;
        qf0 = *(const bf16x8*)qp;
        qf1 = *(const bf16x8*)(qp + 32);
    }

    floatx4 acc_o[4] = {};
    float mreg[4] = {-1e30f, -1e30f, -1e30f, -1e30f};
    float lreg[4] = {};

    for (int s0 = 0; s0 <= q0; s0 += 64) {
        __syncthreads();   // prior PV reads done before overwriting Vt/Pl
        // stage V transposed: Vt[d][key]
        {
            const ushort* vp = qkv + ((size_t)(b * TT + s0 + vkey)) * 1536
                                   + 1024 + h * HSS + vd0;
            bf16x8 v0 = *(const bf16x8*)vp;
            bf16x8 v1 = *(const bf16x8*)(vp + 8);
            #pragma unroll
            for (int j = 0; j < 8; ++j) {
                Vt[vd0 + j][vkey]     = (ushort)v0[j];
                Vt[vd0 + 8 + j][vkey] = (ushort)v1[j];
            }
        }

        // S = Q K^T via MFMA; K B-frags direct from global (col=key=l15, k=d)
        floatx4 s4[4] = {};
        #pragma unroll
        for (int kb = 0; kb < 4; ++kb) {
            const ushort* kp = qkv + ((size_t)(b * TT + s0 + kb * 16 + l15)) * 1536
                                   + 512 + h * HSS + g * 8;
            bf16x8 kf0 = *(const bf16x8*)kp;
            bf16x8 kf1 = *(const bf16x8*)(kp + 32);
            s4[kb] = __builtin_amdgcn_mfma_f32_16x16x32_bf16(qf0, kf0, s4[kb], 0, 0, 0);
            s4[kb] = __builtin_amdgcn_mfma_f32_16x16x32_bf16(qf1, kf1, s4[kb], 0, 0, 0);
        }

        const bool diag = (s0 == q0);
        #pragma unroll
        for (int r = 0; r < 4; ++r) {
            const int qrow = q0 + 16 * w + g * 4 + r;   // global q of this acc row
            float sv[4];
            #pragma unroll
            for (int kb = 0; kb < 4; ++kb) {
                float xs = s4[kb][r] * scale;
                if (diag && (s0 + kb * 16 + l15) > qrow) xs = -1e30f;
                sv[kb] = xs;
            }
            float pm = fmaxf(fmaxf(sv[0], sv[1]), fmaxf(sv[2], sv[3]));
            pm = fmaxf(pm, __shfl_xor(pm, 1));
            pm = fmaxf(pm, __shfl_xor(pm, 2));
            pm = fmaxf(pm, __shfl_xor(pm, 4));
            pm = fmaxf(pm, __shfl_xor(pm, 8));
            float mnew = fmaxf(mreg[r], pm);
            float c = __expf(mreg[r] - mnew);
            float ps = 0.f;
            #pragma unroll
            for (int kb = 0; kb < 4; ++kb) { sv[kb] = __expf(sv[kb] - mnew); ps += sv[kb]; }
            ps += __shfl_xor(ps, 1);
            ps += __shfl_xor(ps, 2);
            ps += __shfl_xor(ps, 4);
            ps += __shfl_xor(ps, 8);
            lreg[r] = lreg[r] * c + ps;
            mreg[r] = mnew;
            #pragma unroll
            for (int db = 0; db < 4; ++db) acc_o[db][r] *= c;
            #pragma unroll
            for (int kb = 0; kb < 4; ++kb)
                Pl[16 * w + g * 4 + r][kb * 16 + l15] = f2bf(sv[kb]);
        }
        __syncthreads();

        // O += P V  (A=P from Pl: row=l15, k=key; B=V from Vt: col=d=l15, k=key)
        bf16x8 pa0 = *(const bf16x8*)&Pl[16 * w + l15][g * 8];
        bf16x8 pa1 = *(const bf16x8*)&Pl[16 * w + l15][g * 8 + 32];
        #pragma unroll
        for (int db = 0; db < 4; ++db) {
            bf16x8 vb0 = *(const bf16x8*)&Vt[db * 16 + l15][g * 8];
            bf16x8 vb1 = *(const bf16x8*)&Vt[db * 16 + l15][g * 8 + 32];
            acc_o[db] = __builtin_amdgcn_mfma_f32_16x16x32_bf16(pa0, vb0, acc_o[db], 0, 0, 0);
            acc_o[db] = __builtin_amdgcn_mfma_f32_16x16x32_bf16(pa1, vb1, acc_o[db], 0, 0, 0);
        }
    }

    #pragma unroll
    for (int r = 0; r < 4; ++r) {
        float inv = 1.0f / lreg[r];
        ushort* op = out + ((size_t)(b * TT + q0 + 16 * w + g * 4 + r)) * DD + h * HSS;
        #pragma unroll
        for (int db = 0; db < 4; ++db)
            op[db * 16 + l15] = f2bf(acc_o[db][r] * inv);
    }
}

// ---------------- per-row -log-softmax[target]
__global__ __launch_bounds__(256)
void rowloss_kernel(const float* __restrict__ logits, const int* __restrict__ targets,
                    float* __restrict__ rowloss)
{
    __shared__ float red[256];
    const int row = blockIdx.x, tid = threadIdx.x;
    const float* lr = logits + (size_t)row * VV;
    float mx = -INFINITY;
    for (int i = tid; i < VV; i += 256) mx = fmaxf(mx, lr[i]);
    red[tid] = mx; __syncthreads();
    for (int s2 = 128; s2; s2 >>= 1) {
        if (tid < s2) red[tid] = fmaxf(red[tid], red[tid + s2]);
        __syncthreads();
    }
    mx = red[0]; __syncthreads();
    float s = 0.f;
    for (int i = tid; i < VV; i += 256) s += __expf(lr[i] - mx);
    red[tid] = s; __syncthreads();
    for (int s2 = 128; s2; s2 >>= 1) {
        if (tid < s2) red[tid] += red[tid + s2];
        __syncthreads();
    }
    if (tid == 0) rowloss[row] = -(lr[targets[row]] - mx - logf(red[0]));
}

__global__ __launch_bounds__(256)
void loss_finalize(const float* __restrict__ rowloss, float* __restrict__ out)
{
    __shared__ float red[256];
    float s = 0.f;
    for (int i = threadIdx.x; i < BB * TT; i += 256) s += rowloss[i];
    red[threadIdx.x] = s; __syncthreads();
    for (int s2 = 128; s2; s2 >>= 1) {
        if (threadIdx.x < s2) red[threadIdx.x] += red[threadIdx.x + s2];
        __syncthreads();
    }
    if (threadIdx.x == 0) out[0] = red[0] * (1.0f / (BB * TT));
}

extern "C" void kernel_launch(void* const* d_in, const int* in_sizes, int n_in,
                              void* d_out, int out_size, void* d_ws, size_t ws_size,
                              hipStream_t stream) {
    const int*   idx     = (const int*)  d_in[0];
    const int*   targets = (const int*)  d_in[1];
    const float* tok_emb = (const float*)d_in[2];
    const float* pos_emb = (const float*)d_in[3];
    const float* ln1_g   = (const float*)d_in[4];
    const float* ln1_b   = (const float*)d_in[5];
    const float* Wq      = (const float*)d_in[6];
    const float* Wk      = (const float*)d_in[7];
    const float* Wv      = (const float*)d_in[8];
    const float* Wo      = (const float*)d_in[9];
    const float* bo      = (const float*)d_in[10];
    const float* ln2_g   = (const float*)d_in[11];
    const float* ln2_b   = (const float*)d_in[12];
    const float* W1      = (const float*)d_in[13];
    const float* b1      = (const float*)d_in[14];
    const float* W2      = (const float*)d_in[15];
    const float* b2      = (const float*)d_in[16];
    const float* lnf_g   = (const float*)d_in[17];
    const float* lnf_b   = (const float*)d_in[18];
    const float* Wout    = (const float*)d_in[19];
    const float* bout    = (const float*)d_in[20];

    float* outf   = (float*)d_out;
    float* logits = outf + 1;                   // [B*T, V] fp32

    const size_t ROW = (size_t)BB * TT;         // 4096

    // ---- d_ws: x (fp32) | h_bf | Wout^T (bf16) | rowloss
    float*  x     = (float*)d_ws;
    ushort* h_bf  = (ushort*)(x + ROW * DD);
    ushort* Woutt = h_bf + ROW * DD;
    float*  rowloss = (float*)(Woutt + (size_t)VV * DD);

    // ---- scratch inside the (dead-until-final) logits region of d_out
    ushort* sc     = (ushort*)(outf + 8);
    ushort* qkv_bf = sc;                        // ROW*1536
    ushort* ff_bf  = qkv_bf + ROW * 1536;       // ROW*2048
    ushort* Wqkvt  = ff_bf + ROW * FF_;         // L*1536*512
    ushort* Wot    = Wqkvt + (size_t)LL * 1536 * DD;
    ushort* W1t    = Wot   + (size_t)LL * DD * DD;
    ushort* W2t    = W1t   + (size_t)LL * FF_ * DD;

    qkv_transpose<<<dim3(8, 96), 256, 0, stream>>>(Wq, Wk, Wv, Wqkvt);
    transpose_cvt<<<dim3(8, 8, LL),  256, 0, stream>>>(Wo,   Wot,   DD,  DD,  (long)DD*DD,   (long)DD*DD);
    transpose_cvt<<<dim3(32, 8, LL), 256, 0, stream>>>(W1,   W1t,   FF_, DD,  (long)DD*FF_,  (long)DD*FF_);
    transpose_cvt<<<dim3(8, 32, LL), 256, 0, stream>>>(W2,   W2t,   DD,  FF_, (long)FF_*DD,  (long)FF_*DD);
    transpose_cvt<<<dim3(500, 8, 1), 256, 0, stream>>>(Wout, Woutt, VV,  DD,  0, 0);

    embed_kernel<<<ROW, 64, 0, stream>>>(idx, tok_emb, pos_emb, x);

    for (int l = 0; l < LL; ++l) {
        ln_kernel<<<ROW / 4, 256, 0, stream>>>(x, ln1_g + l * DD, ln1_b + l * DD, h_bf);

        mfma_gemm<<<dim3(1536 / 128, ROW / 128), 256, 0, stream>>>(
            h_bf, DD, Wqkvt + (size_t)l * 1536 * DD, DD,
            nullptr, qkv_bf, 1536, nullptr, nullptr, 0, DD, 0, 0);

        attn_mfma_kernel<<<dim3(TT / 64, BB * HH), 256, 0, stream>>>(qkv_bf, h_bf);

        mfma_gemm<<<dim3(DD / 128, ROW / 128), 256, 0, stream>>>(
            h_bf, DD, Wot + (size_t)l * DD * DD, DD,
            x, nullptr, DD, bo + l * DD, x, DD, DD, 0, 0);

        ln_kernel<<<ROW / 4, 256, 0, stream>>>(x, ln2_g + l * DD, ln2_b + l * DD, h_bf);

        mfma_gemm<<<dim3(FF_ / 128, ROW / 128), 256, 0, stream>>>(
            h_bf, DD, W1t + (size_t)l * FF_ * DD, DD,
            nullptr, ff_bf, FF_, b1 + l * FF_, nullptr, 0, DD, 1, 0);

        mfma_gemm<<<dim3(DD / 128, ROW / 128), 256, 0, stream>>>(
            ff_bf, FF_, W2t + (size_t)l * DD * FF_, FF_,
            x, nullptr, DD, b2 + l * DD, x, DD, FF_, 0, 0);
    }

    ln_kernel<<<ROW / 4, 256, 0, stream>>>(x, lnf_g, lnf_b, h_bf);

    // logits: M-fast grid so consecutive blocks share the B-panel (L2 reuse)
    mfma_gemm<<<dim3(ROW / 128, VV / 128), 256, 0, stream>>>(
        h_bf, DD, Woutt, DD,
        logits, nullptr, VV, bout, nullptr, 0, DD, 0, 1);

    rowloss_kernel<<<ROW, 256, 0, stream>>>(logits, targets, rowloss);
    loss_finalize<<<1, 256, 0, stream>>>(rowloss, outf);
}

// Round 6
// 1619.246 us; speedup vs baseline: 9.0926x; 1.2325x over previous
//
#include <hip/hip_runtime.h>
#include <hip/hip_bf16.h>
#include <math.h>

#define TT 2048
#define BB 2
#define VV 32000
#define DD 512
#define HH 8
#define HSS 64
#define LL 4
#define FF_ 2048
#define NBLK_V (VV / 128)   // 250

using bf16x8 = __attribute__((ext_vector_type(8))) short;
using floatx4 = __attribute__((ext_vector_type(4))) float;

__device__ __forceinline__ ushort f2bf(float f) {
    __hip_bfloat16 b = __float2bfloat16(f);
    return *reinterpret_cast<ushort*>(&b);
}
__device__ __forceinline__ float bf2f(ushort u) {
    union { unsigned int i; float f; } x; x.i = ((unsigned int)u) << 16; return x.f;
}
__device__ __forceinline__ void gload16(const void* g, void* l) {
    __builtin_amdgcn_global_load_lds(
        (const __attribute__((address_space(1))) void*)g,
        (__attribute__((address_space(3))) void*)l, 16, 0, 0);
}

// ---------------- embedding
__global__ __launch_bounds__(64)
void embed_kernel(const int* __restrict__ idx, const float* __restrict__ tok,
                  const float* __restrict__ pos, float* __restrict__ x)
{
    int row = blockIdx.x;
    int t = row & (TT - 1);
    int tokid = idx[row];
    int lane = threadIdx.x;
    const float4* tp = (const float4*)(tok + (size_t)tokid * DD);
    const float4* pp = (const float4*)(pos + (size_t)t * DD);
    float4* xp = (float4*)(x + (size_t)row * DD);
    int i0 = lane * 2;
    float4 a = tp[i0],   b4 = pp[i0];
    float4 c = tp[i0+1], d4 = pp[i0+1];
    xp[i0]   = make_float4(a.x + b4.x, a.y + b4.y, a.z + b4.z, a.w + b4.w);
    xp[i0+1] = make_float4(c.x + d4.x, c.y + d4.y, c.z + d4.z, c.w + d4.w);
}

// ---------------- layernorm -> bf16
__global__ __launch_bounds__(256)
void ln_kernel(const float* __restrict__ x, const float* __restrict__ g,
               const float* __restrict__ b, ushort* __restrict__ out)
{
    int wave = threadIdx.x >> 6;
    int lane = threadIdx.x & 63;
    int row  = blockIdx.x * 4 + wave;
    const float* xr = x + (size_t)row * DD;
    float4 v0 = *(const float4*)(xr + lane * 8);
    float4 v1 = *(const float4*)(xr + lane * 8 + 4);
    float s = v0.x + v0.y + v0.z + v0.w + v1.x + v1.y + v1.z + v1.w;
    float q = v0.x*v0.x + v0.y*v0.y + v0.z*v0.z + v0.w*v0.w
            + v1.x*v1.x + v1.y*v1.y + v1.z*v1.z + v1.w*v1.w;
    #pragma unroll
    for (int off = 32; off; off >>= 1) {
        s += __shfl_xor(s, off);
        q += __shfl_xor(q, off);
    }
    float mu  = s * (1.0f / DD);
    float var = q * (1.0f / DD) - mu * mu;
    float rs  = rsqrtf(var + 1e-5f);
    float4 g0 = *(const float4*)(g + lane * 8);
    float4 g1 = *(const float4*)(g + lane * 8 + 4);
    float4 b0 = *(const float4*)(b + lane * 8);
    float4 b1 = *(const float4*)(b + lane * 8 + 4);
    union { ushort u[8]; uint4 v; } pk;
    pk.u[0] = f2bf((v0.x - mu) * rs * g0.x + b0.x);
    pk.u[1] = f2bf((v0.y - mu) * rs * g0.y + b0.y);
    pk.u[2] = f2bf((v0.z - mu) * rs * g0.z + b0.z);
    pk.u[3] = f2bf((v0.w - mu) * rs * g0.w + b0.w);
    pk.u[4] = f2bf((v1.x - mu) * rs * g1.x + b1.x);
    pk.u[5] = f2bf((v1.y - mu) * rs * g1.y + b1.y);
    pk.u[6] = f2bf((v1.z - mu) * rs * g1.z + b1.z);
    pk.u[7] = f2bf((v1.w - mu) * rs * g1.w + b1.w);
    *(uint4*)(out + (size_t)row * DD + lane * 8) = pk.v;
}

// ---------------- transpose+convert: in [K][N] f32 -> out [N][K] bf16
__global__ __launch_bounds__(256)
void transpose_cvt(const float* __restrict__ in, ushort* __restrict__ out,
                   int N, int K, long inStrideZ, long outStrideZ)
{
    __shared__ float t[64][65];
    in  += (size_t)blockIdx.z * inStrideZ;
    out += (size_t)blockIdx.z * outStrideZ;
    const int n0 = blockIdx.x * 64, k0 = blockIdx.y * 64;
    const int r = threadIdx.x >> 2;
    const int c = (threadIdx.x & 3) * 16;
    #pragma unroll
    for (int j = 0; j < 16; j += 4) {
        float4 v = *(const float4*)&in[(size_t)(k0 + r) * N + n0 + c + j];
        t[r][c + j + 0] = v.x; t[r][c + j + 1] = v.y;
        t[r][c + j + 2] = v.z; t[r][c + j + 3] = v.w;
    }
    __syncthreads();
    union { ushort u[8]; uint4 v; } pk;
    ushort* orow = out + (size_t)(n0 + r) * K + k0 + c;
    #pragma unroll
    for (int half = 0; half < 2; ++half) {
        #pragma unroll
        for (int j = 0; j < 8; ++j) pk.u[j] = f2bf(t[c + half * 8 + j][r]);
        *(uint4*)(orow + half * 8) = pk.v;
    }
}

// ---------------- QKV weights -> fused [L][1536][512] bf16
__global__ __launch_bounds__(256)
void qkv_transpose(const float* __restrict__ Wq, const float* __restrict__ Wk,
                   const float* __restrict__ Wv, ushort* __restrict__ out)
{
    __shared__ float t[64][65];
    const int z = blockIdx.y;
    const int sel = z >> 5, l = (z >> 3) & 3, h = z & 7;
    const float* in = (sel == 0 ? Wq : sel == 1 ? Wk : Wv)
                      + (size_t)l * (HH * DD * HSS) + (size_t)h * (DD * HSS);
    ushort* ob = out + (size_t)l * (3 * DD * DD) + (size_t)sel * (DD * DD)
                     + (size_t)h * (HSS * DD);
    const int d0 = blockIdx.x * 64;
    const int r = threadIdx.x >> 2;
    const int c = (threadIdx.x & 3) * 16;
    #pragma unroll
    for (int j = 0; j < 16; j += 4) {
        float4 v = *(const float4*)&in[(size_t)(d0 + r) * HSS + c + j];
        t[r][c + j + 0] = v.x; t[r][c + j + 1] = v.y;
        t[r][c + j + 2] = v.z; t[r][c + j + 3] = v.w;
    }
    __syncthreads();
    union { ushort u[8]; uint4 v; } pk;
    ushort* orow = ob + (size_t)r * DD + d0 + c;
    #pragma unroll
    for (int half = 0; half < 2; ++half) {
        #pragma unroll
        for (int j = 0; j < 8; ++j) pk.u[j] = f2bf(t[c + half * 8 + j][r]);
        *(uint4*)(orow + half * 8) = pk.v;
    }
}

// ---------------- bf16 MFMA GEMM with LDS-staged vectorized epilogue
// C = A[M,K] @ Bt[N,K]^T (+bias)(+resid at writeout)(relu)
// smax/ssum non-null (logits): also emit per-(row,128-block) max / sumexp.
__global__ __launch_bounds__(256)
void mfma_gemm(const ushort* __restrict__ A, int lda,
               const ushort* __restrict__ Bt, int ldb,
               float* __restrict__ Cf, ushort* __restrict__ Cbf, int ldc,
               const float* __restrict__ bias,
               const float* __restrict__ resid, int ldres,
               int K, int relu, int mswap,
               float* __restrict__ smax, float* __restrict__ ssum, int nblks)
{
    __shared__ union {
        ushort stage[2][16 * 512];   // As | Bs (32 KB)
        ushort cu[128][136];         // bf16 C tile (34 KB)
        float  cf[64][136];          // fp32 C half-tile (34 KB)
    } sh;

    const int bxx = mswap ? blockIdx.y : blockIdx.x;
    const int byy = mswap ? blockIdx.x : blockIdx.y;
    const int m0 = byy << 7, n0 = bxx << 7;
    const int tid = threadIdx.x, w = tid >> 6, lane = tid & 63;
    const int wm = w >> 1, wn = w & 1;
    const int l15 = lane & 15, lk = lane >> 4;

    floatx4 acc[4][4] = {};

    ushort* As = sh.stage[0];
    ushort* Bs = sh.stage[1];

    for (int k0 = 0; k0 < K; k0 += 64) {
        #pragma unroll
        for (int i = 0; i < 4; ++i) {
            int c = 4 * w + i;
            int cg = c >> 3, cmi = (c >> 1) & 3, ckh = c & 1;
            const ushort* ga = A + (size_t)(m0 + cg * 64 + cmi * 16 + l15) * lda
                                 + k0 + lk * 8 + ckh * 32;
            gload16(ga, &As[c * 512]);
            const ushort* gb = Bt + (size_t)(n0 + cg * 64 + cmi * 16 + l15) * ldb
                                  + k0 + lk * 8 + ckh * 32;
            gload16(gb, &Bs[c * 512]);
        }
        __syncthreads();
        #pragma unroll
        for (int kh = 0; kh < 2; ++kh) {
            bf16x8 af[4], bfr[4];
            #pragma unroll
            for (int mi = 0; mi < 4; ++mi)
                af[mi] = *(const bf16x8*)&As[((wm * 8 + mi * 2 + kh) * 64 + lane) * 8];
            #pragma unroll
            for (int ni = 0; ni < 4; ++ni)
                bfr[ni] = *(const bf16x8*)&Bs[((wn * 8 + ni * 2 + kh) * 64 + lane) * 8];
            #pragma unroll
            for (int mi = 0; mi < 4; ++mi)
                #pragma unroll
                for (int ni = 0; ni < 4; ++ni)
                    acc[mi][ni] = __builtin_amdgcn_mfma_f32_16x16x32_bf16(
                        af[mi], bfr[ni], acc[mi][ni], 0, 0, 0);
        }
        __syncthreads();
    }

    // bias/relu applied in registers
    #pragma unroll
    for (int mi = 0; mi < 4; ++mi)
        #pragma unroll
        for (int ni = 0; ni < 4; ++ni)
            #pragma unroll
            for (int r = 0; r < 4; ++r) {
                float v = acc[mi][ni][r];
                if (bias) v += bias[n0 + wn * 64 + ni * 16 + l15];
                if (relu) v = fmaxf(v, 0.0f);
                acc[mi][ni][r] = v;
            }

    if (Cbf) {
        // ---- bf16 epilogue: stage whole 128x128 tile, write uint4 rows
        #pragma unroll
        for (int mi = 0; mi < 4; ++mi)
            #pragma unroll
            for (int ni = 0; ni < 4; ++ni)
                #pragma unroll
                for (int r = 0; r < 4; ++r)
                    sh.cu[wm * 64 + mi * 16 + lk * 4 + r][wn * 64 + ni * 16 + l15]
                        = f2bf(acc[mi][ni][r]);
        __syncthreads();
        const int rr = tid >> 1, hh = tid & 1;
        ushort* gp = Cbf + (size_t)(m0 + rr) * ldc + n0 + hh * 64;
        #pragma unroll
        for (int j = 0; j < 8; ++j)
            *(uint4*)(gp + j * 8) = *(uint4*)&sh.cu[rr][hh * 64 + j * 8];
    } else {
        // ---- fp32 epilogue in two 64-row halves
        const int rr = tid >> 2, qd = tid & 3;
        const bool dosm = (smax != nullptr);
        #pragma unroll
        for (int h = 0; h < 2; ++h) {
            if (h) __syncthreads();
            if (wm == h) {
                #pragma unroll
                for (int mi = 0; mi < 4; ++mi)
                    #pragma unroll
                    for (int ni = 0; ni < 4; ++ni)
                        #pragma unroll
                        for (int r = 0; r < 4; ++r)
                            sh.cf[mi * 16 + lk * 4 + r][wn * 64 + ni * 16 + l15]
                                = acc[mi][ni][r];
            }
            __syncthreads();
            const int grow = m0 + h * 64 + rr;
            float* gp = Cf + (size_t)grow * ldc + n0 + qd * 32;
            float lmax = -1e30f;
            #pragma unroll
            for (int j = 0; j < 8; ++j) {
                float4 v4 = *(float4*)&sh.cf[rr][qd * 32 + j * 4];
                if (resid) {
                    const float4 rv = *(const float4*)&resid[(size_t)grow * ldres
                                                             + n0 + qd * 32 + j * 4];
                    v4.x += rv.x; v4.y += rv.y; v4.z += rv.z; v4.w += rv.w;
                }
                *(float4*)(gp + j * 4) = v4;
                if (dosm)
                    lmax = fmaxf(lmax, fmaxf(fmaxf(v4.x, v4.y), fmaxf(v4.z, v4.w)));
            }
            if (dosm) {
                lmax = fmaxf(lmax, __shfl_xor(lmax, 1));
                lmax = fmaxf(lmax, __shfl_xor(lmax, 2));
                float lsum = 0.f;
                #pragma unroll
                for (int j = 0; j < 8; ++j) {
                    float4 v4 = *(float4*)&sh.cf[rr][qd * 32 + j * 4];
                    lsum += __expf(v4.x - lmax) + __expf(v4.y - lmax)
                          + __expf(v4.z - lmax) + __expf(v4.w - lmax);
                }
                lsum += __shfl_xor(lsum, 1);
                lsum += __shfl_xor(lsum, 2);
                if (qd == 0) {
                    smax[(size_t)grow * nblks + bxx] = lmax;
                    ssum[(size_t)grow * nblks + bxx] = lsum;
                }
            }
        }
    }
}

// ---------------- MFMA flash attention (bf16 MFMA, fp32 softmax)
__global__ __launch_bounds__(256)
void attn_mfma_kernel(const ushort* __restrict__ qkv, ushort* __restrict__ out)
{
    __shared__ ushort Vt[64][72];   // Vt[d][key]
    __shared__ ushort Pl[64][72];   // P[q_local][key]

    const int z = blockIdx.y, b = z >> 3, h = z & 7;
    const int q0 = blockIdx.x << 6;
    const int tid = threadIdx.x;
    const int w = tid >> 6, lane = tid & 63;
    const int l15 = lane & 15, g = lane >> 4;
    const float scale = 0.04419417382415922f;  // 1/sqrt(512)

    const int vkey = tid & 63, vd0 = (tid >> 6) * 16;

    bf16x8 qf0, qf1;
    {
        const ushort* qp = qkv + ((size_t)(b * TT + q0 + 16 * w + l15)) * 1536
                               + h * HSS + g * 8;
        qf0 = *(const bf16x8*)qp;
        qf1 = *(const bf16x8*)(qp + 32);
    }

    floatx4 acc_o[4] = {};
    float mreg[4] = {-1e30f, -1e30f, -1e30f, -1e30f};
    float lreg[4] = {};

    for (int s0 = 0; s0 <= q0; s0 += 64) {
        __syncthreads();
        {
            const ushort* vp = qkv + ((size_t)(b * TT + s0 + vkey)) * 1536
                                   + 1024 + h * HSS + vd0;
            bf16x8 v0 = *(const bf16x8*)vp;
            bf16x8 v1 = *(const bf16x8*)(vp + 8);
            #pragma unroll
            for (int j = 0; j < 8; ++j) {
                Vt[vd0 + j][vkey]     = (ushort)v0[j];
                Vt[vd0 + 8 + j][vkey] = (ushort)v1[j];
            }
        }

        floatx4 s4[4] = {};
        #pragma unroll
        for (int kb = 0; kb < 4; ++kb) {
            const ushort* kp = qkv + ((size_t)(b * TT + s0 + kb * 16 + l15)) * 1536
                                   + 512 + h * HSS + g * 8;
            bf16x8 kf0 = *(const bf16x8*)kp;
            bf16x8 kf1 = *(const bf16x8*)(kp + 32);
            s4[kb] = __builtin_amdgcn_mfma_f32_16x16x32_bf16(qf0, kf0, s4[kb], 0, 0, 0);
            s4[kb] = __builtin_amdgcn_mfma_f32_16x16x32_bf16(qf1, kf1, s4[kb], 0, 0, 0);
        }

        const bool diag = (s0 == q0);
        #pragma unroll
        for (int r = 0; r < 4; ++r) {
            const int qrow = q0 + 16 * w + g * 4 + r;
            float sv[4];
            #pragma unroll
            for (int kb = 0; kb < 4; ++kb) {
                float xs = s4[kb][r] * scale;
                if (diag && (s0 + kb * 16 + l15) > qrow) xs = -1e30f;
                sv[kb] = xs;
            }
            float pm = fmaxf(fmaxf(sv[0], sv[1]), fmaxf(sv[2], sv[3]));
            pm = fmaxf(pm, __shfl_xor(pm, 1));
            pm = fmaxf(pm, __shfl_xor(pm, 2));
            pm = fmaxf(pm, __shfl_xor(pm, 4));
            pm = fmaxf(pm, __shfl_xor(pm, 8));
            float mnew = fmaxf(mreg[r], pm);
            float c = __expf(mreg[r] - mnew);
            float ps = 0.f;
            #pragma unroll
            for (int kb = 0; kb < 4; ++kb) { sv[kb] = __expf(sv[kb] - mnew); ps += sv[kb]; }
            ps += __shfl_xor(ps, 1);
            ps += __shfl_xor(ps, 2);
            ps += __shfl_xor(ps, 4);
            ps += __shfl_xor(ps, 8);
            lreg[r] = lreg[r] * c + ps;
            mreg[r] = mnew;
            #pragma unroll
            for (int db = 0; db < 4; ++db) acc_o[db][r] *= c;
            #pragma unroll
            for (int kb = 0; kb < 4; ++kb)
                Pl[16 * w + g * 4 + r][kb * 16 + l15] = f2bf(sv[kb]);
        }
        __syncthreads();

        bf16x8 pa0 = *(const bf16x8*)&Pl[16 * w + l15][g * 8];
        bf16x8 pa1 = *(const bf16x8*)&Pl[16 * w + l15][g * 8 + 32];
        #pragma unroll
        for (int db = 0; db < 4; ++db) {
            bf16x8 vb0 = *(const bf16x8*)&Vt[db * 16 + l15][g * 8];
            bf16x8 vb1 = *(const bf16x8*)&Vt[db * 16 + l15][g * 8 + 32];
            acc_o[db] = __builtin_amdgcn_mfma_f32_16x16x32_bf16(pa0, vb0, acc_o[db], 0, 0, 0);
            acc_o[db] = __builtin_amdgcn_mfma_f32_16x16x32_bf16(pa1, vb1, acc_o[db], 0, 0, 0);
        }
    }

    #pragma unroll
    for (int r = 0; r < 4; ++r) {
        float inv = 1.0f / lreg[r];
        ushort* op = out + ((size_t)(b * TT + q0 + 16 * w + g * 4 + r)) * DD + h * HSS;
        #pragma unroll
        for (int db = 0; db < 4; ++db)
            op[db * 16 + l15] = f2bf(acc_o[db][r] * inv);
    }
}

// ---------------- combine per-block softmax partials into per-row loss
__global__ __launch_bounds__(256)
void rowloss_finalize(const float* __restrict__ logits, const int* __restrict__ targets,
                      const float* __restrict__ smax, const float* __restrict__ ssum,
                      float* __restrict__ rowloss)
{
    const int wv = threadIdx.x >> 6, lane = threadIdx.x & 63;
    const int row = blockIdx.x * 4 + wv;
    const float* mrow = smax + (size_t)row * NBLK_V;
    const float* srow = ssum + (size_t)row * NBLK_V;
    float M = -1e30f;
    for (int i = lane; i < NBLK_V; i += 64) M = fmaxf(M, mrow[i]);
    #pragma unroll
    for (int off = 32; off; off >>= 1) M = fmaxf(M, __shfl_xor(M, off));
    float S = 0.f;
    for (int i = lane; i < NBLK_V; i += 64) S += srow[i] * __expf(mrow[i] - M);
    #pragma unroll
    for (int off = 32; off; off >>= 1) S += __shfl_xor(S, off);
    if (lane == 0)
        rowloss[row] = -(logits[(size_t)row * VV + targets[row]] - M - logf(S));
}

__global__ __launch_bounds__(256)
void loss_finalize(const float* __restrict__ rowloss, float* __restrict__ out)
{
    __shared__ float red[256];
    float s = 0.f;
    for (int i = threadIdx.x; i < BB * TT; i += 256) s += rowloss[i];
    red[threadIdx.x] = s; __syncthreads();
    for (int s2 = 128; s2; s2 >>= 1) {
        if (threadIdx.x < s2) red[threadIdx.x] += red[threadIdx.x + s2];
        __syncthreads();
    }
    if (threadIdx.x == 0) out[0] = red[0] * (1.0f / (BB * TT));
}

extern "C" void kernel_launch(void* const* d_in, const int* in_sizes, int n_in,
                              void* d_out, int out_size, void* d_ws, size_t ws_size,
                              hipStream_t stream) {
    const int*   idx     = (const int*)  d_in[0];
    const int*   targets = (const int*)  d_in[1];
    const float* tok_emb = (const float*)d_in[2];
    const float* pos_emb = (const float*)d_in[3];
    const float* ln1_g   = (const float*)d_in[4];
    const float* ln1_b   = (const float*)d_in[5];
    const float* Wq      = (const float*)d_in[6];
    const float* Wk      = (const float*)d_in[7];
    const float* Wv      = (const float*)d_in[8];
    const float* Wo      = (const float*)d_in[9];
    const float* bo      = (const float*)d_in[10];
    const float* ln2_g   = (const float*)d_in[11];
    const float* ln2_b   = (const float*)d_in[12];
    const float* W1      = (const float*)d_in[13];
    const float* b1      = (const float*)d_in[14];
    const float* W2      = (const float*)d_in[15];
    const float* b2      = (const float*)d_in[16];
    const float* lnf_g   = (const float*)d_in[17];
    const float* lnf_b   = (const float*)d_in[18];
    const float* Wout    = (const float*)d_in[19];
    const float* bout    = (const float*)d_in[20];

    float* outf   = (float*)d_out;
    float* logits = outf + 1;                   // [B*T, V] fp32

    const size_t ROW = (size_t)BB * TT;         // 4096

    // ---- d_ws: x (fp32) | h_bf | Wout^T (bf16) | rowloss
    float*  x     = (float*)d_ws;
    ushort* h_bf  = (ushort*)(x + ROW * DD);
    ushort* Woutt = h_bf + ROW * DD;
    float*  rowloss = (float*)(Woutt + (size_t)VV * DD);
    // x is dead after the final ln_kernel -> reuse for softmax partials
    float* smax = x;                            // ROW * NBLK_V
    float* ssum = x + ROW * NBLK_V;             // ROW * NBLK_V

    // ---- scratch inside the (dead-until-final) logits region of d_out
    ushort* sc     = (ushort*)(outf + 8);
    ushort* qkv_bf = sc;                        // ROW*1536
    ushort* ff_bf  = qkv_bf + ROW * 1536;       // ROW*2048
    ushort* Wqkvt  = ff_bf + ROW * FF_;         // L*1536*512
    ushort* Wot    = Wqkvt + (size_t)LL * 1536 * DD;
    ushort* W1t    = Wot   + (size_t)LL * DD * DD;
    ushort* W2t    = W1t   + (size_t)LL * FF_ * DD;

    qkv_transpose<<<dim3(8, 96), 256, 0, stream>>>(Wq, Wk, Wv, Wqkvt);
    transpose_cvt<<<dim3(8, 8, LL),  256, 0, stream>>>(Wo,   Wot,   DD,  DD,  (long)DD*DD,   (long)DD*DD);
    transpose_cvt<<<dim3(32, 8, LL), 256, 0, stream>>>(W1,   W1t,   FF_, DD,  (long)DD*FF_,  (long)DD*FF_);
    transpose_cvt<<<dim3(8, 32, LL), 256, 0, stream>>>(W2,   W2t,   DD,  FF_, (long)FF_*DD,  (long)FF_*DD);
    transpose_cvt<<<dim3(500, 8, 1), 256, 0, stream>>>(Wout, Woutt, VV,  DD,  0, 0);

    embed_kernel<<<ROW, 64, 0, stream>>>(idx, tok_emb, pos_emb, x);

    for (int l = 0; l < LL; ++l) {
        ln_kernel<<<ROW / 4, 256, 0, stream>>>(x, ln1_g + l * DD, ln1_b + l * DD, h_bf);

        mfma_gemm<<<dim3(1536 / 128, ROW / 128), 256, 0, stream>>>(
            h_bf, DD, Wqkvt + (size_t)l * 1536 * DD, DD,
            nullptr, qkv_bf, 1536, nullptr, nullptr, 0, DD, 0, 0,
            nullptr, nullptr, 0);

        attn_mfma_kernel<<<dim3(TT / 64, BB * HH), 256, 0, stream>>>(qkv_bf, h_bf);

        mfma_gemm<<<dim3(DD / 128, ROW / 128), 256, 0, stream>>>(
            h_bf, DD, Wot + (size_t)l * DD * DD, DD,
            x, nullptr, DD, bo + l * DD, x, DD, DD, 0, 0,
            nullptr, nullptr, 0);

        ln_kernel<<<ROW / 4, 256, 0, stream>>>(x, ln2_g + l * DD, ln2_b + l * DD, h_bf);

        mfma_gemm<<<dim3(FF_ / 128, ROW / 128), 256, 0, stream>>>(
            h_bf, DD, W1t + (size_t)l * FF_ * DD, DD,
            nullptr, ff_bf, FF_, b1 + l * FF_, nullptr, 0, DD, 1, 0,
            nullptr, nullptr, 0);

        mfma_gemm<<<dim3(DD / 128, ROW / 128), 256, 0, stream>>>(
            ff_bf, FF_, W2t + (size_t)l * DD * FF_, FF_,
            x, nullptr, DD, b2 + l * DD, x, DD, FF_, 0, 0,
            nullptr, nullptr, 0);
    }

    ln_kernel<<<ROW / 4, 256, 0, stream>>>(x, lnf_g, lnf_b, h_bf);

    // logits GEMM (M-fast for B-panel L2 reuse) + fused softmax partials
    mfma_gemm<<<dim3(ROW / 128, VV / 128), 256, 0, stream>>>(
        h_bf, DD, Woutt, DD,
        logits, nullptr, VV, bout, nullptr, 0, DD, 0, 1,
        smax, ssum, NBLK_V);

    rowloss_finalize<<<ROW / 4, 256, 0, stream>>>(logits, targets, smax, ssum, rowloss);
    loss_finalize<<<1, 256, 0, stream>>>(rowloss, outf);
}